// Round 6
// baseline (513.471 us; speedup 1.0000x reference)
//
#include <hip/hip_runtime.h>
#include <math.h>

typedef unsigned short ushort_t;
typedef __attribute__((ext_vector_type(4))) float f32x4;
typedef __attribute__((ext_vector_type(8))) __bf16 bf16x8;
typedef __attribute__((ext_vector_type(8))) unsigned short u16x8;
typedef __attribute__((ext_vector_type(4))) unsigned short u16x4;

#define DEV __device__ __forceinline__

// B=4, L=2048, D=1024, H=16, HD=64, M=B*L=8192
#define CB 4
#define CL 2048
#define CD 1024
#define CM 8192

DEV float bf2f(ushort_t u) {
  unsigned int x = ((unsigned int)u) << 16;
  return __builtin_bit_cast(float, x);
}
DEV ushort_t f2bf(float f) {
  unsigned int u = __builtin_bit_cast(unsigned int, f);
  u += 0x7FFFu + ((u >> 16) & 1u);
  return (ushort_t)(u >> 16);
}
DEV void gload16(const void* g, void* l) {
  __builtin_amdgcn_global_load_lds((const __attribute__((address_space(1))) void*)g,
                                   (__attribute__((address_space(3))) void*)l, 16, 0, 0);
}
// read one 16B MFMA fragment from a [rows][64] ushort LDS tile with XOR(row&7) slot swizzle
DEV bf16x8 frag64(const ushort_t* s, int row, int slog) {
  int sl = slog ^ (row & 7);
  return __builtin_bit_cast(bf16x8, *reinterpret_cast<const u16x8*>(s + row * 64 + sl * 8));
}

// ---------- prep: all weight transposes + rope tables in ONE dispatch ----------
DEV void tr_tile(const float* __restrict__ src, ushort_t* __restrict__ dst, int R, int C, int bx,
                 int by, int t) {
  __shared__ float tile[32][33];
  int c0 = bx * 32, r0 = by * 32;
  int tx = t & 31, ty = t >> 5;  // 32 x 8
#pragma unroll
  for (int i = 0; i < 32; i += 8) tile[ty + i][tx] = src[(size_t)(r0 + ty + i) * C + c0 + tx];
  __syncthreads();
#pragma unroll
  for (int i = 0; i < 32; i += 8) dst[(size_t)(c0 + ty + i) * R + r0 + tx] = f2bf(tile[tx][ty + i]);
}

__global__ __launch_bounds__(256) void k_prep(const float* __restrict__ W_act,
                                              const float* __restrict__ W_in,
                                              const float* __restrict__ W_qk,
                                              const float* __restrict__ W_out,
                                              const float* __restrict__ W1,
                                              const float* __restrict__ W2,
                                              ushort_t* __restrict__ WabT,
                                              ushort_t* __restrict__ WqkT,
                                              ushort_t* __restrict__ WoutT,
                                              ushort_t* __restrict__ W1T,
                                              ushort_t* __restrict__ W2T,
                                              ushort_t* __restrict__ cosT,
                                              ushort_t* __restrict__ sinT) {
  int bid = blockIdx.x, t = threadIdx.x;
  if (bid < 4096) {  // rope tables: L*512 entries
    int idx = bid * 256 + t;
    int l = idx >> 9, j = idx & 511;
    float theta = exp2f(-(float)j * (13.2877123795494f / 512.0f));
    float ang = (float)l * theta;
    float s, c;
    sincosf(ang, &s, &c);
    cosT[idx] = f2bf(c);
    sinT[idx] = f2bf(s);
  } else if (bid < 5120) {
    int lo = bid - 4096;
    tr_tile(W_act, WabT, 1024, 1024, lo & 31, lo >> 5, t);
  } else if (bid < 6144) {
    int lo = bid - 5120;
    tr_tile(W_in, WabT + (size_t)1024 * 1024, 1024, 1024, lo & 31, lo >> 5, t);
  } else if (bid < 8192) {
    int lo = bid - 6144;
    tr_tile(W_qk, WqkT, 1024, 2048, lo & 63, lo >> 6, t);
  } else if (bid < 9216) {
    int lo = bid - 8192;
    tr_tile(W_out, WoutT, 1024, 1024, lo & 31, lo >> 5, t);
  } else if (bid < 13312) {
    int lo = bid - 9216;
    tr_tile(W1, W1T, 1024, 4096, lo & 127, lo >> 7, t);
  } else {
    int lo = bid - 13312;
    tr_tile(W2, W2T, 4096, 1024, lo & 31, lo >> 5, t);
  }
}

// ---------- layernorm: fp32 in -> bf16 out ----------
__global__ __launch_bounds__(256) void k_layernorm(const float* __restrict__ x,
                                                   const float* __restrict__ g,
                                                   const float* __restrict__ b,
                                                   ushort_t* __restrict__ out) {
  int row = blockIdx.x, t = threadIdx.x;
  const float* xr = x + (size_t)row * CD;
  f32x4 v = ((const f32x4*)xr)[t];
  float s = v.x + v.y + v.z + v.w;
  float s2 = v.x * v.x + v.y * v.y + v.z * v.z + v.w * v.w;
#pragma unroll
  for (int off = 32; off >= 1; off >>= 1) {
    s += __shfl_xor(s, off);
    s2 += __shfl_xor(s2, off);
  }
  __shared__ float red[8];
  int lane = t & 63, w = t >> 6;
  if (lane == 0) { red[w] = s; red[w + 4] = s2; }
  __syncthreads();
  s = red[0] + red[1] + red[2] + red[3];
  s2 = red[4] + red[5] + red[6] + red[7];
  float mu = s * (1.0f / CD);
  float var = s2 * (1.0f / CD) - mu * mu;
  float rs = rsqrtf(var + 1e-12f);
  f32x4 gg = ((const f32x4*)g)[t];
  f32x4 bb = ((const f32x4*)b)[t];
  u16x4 o;
  o.x = f2bf((v.x - mu) * rs * gg.x + bb.x);
  o.y = f2bf((v.y - mu) * rs * gg.y + bb.y);
  o.z = f2bf((v.z - mu) * rs * gg.z + bb.z);
  o.w = f2bf((v.w - mu) * rs * gg.w + bb.w);
  ((u16x4*)(out + (size_t)row * CD))[t] = o;
}

// ---------- fused residual+bias+splitK-partials then layernorm ----------
__global__ __launch_bounds__(256) void k_addln(const float* __restrict__ x,
                                               const float* __restrict__ bo,
                                               const float* __restrict__ P,
                                               const float* __restrict__ g,
                                               const float* __restrict__ b,
                                               float* __restrict__ x2,
                                               ushort_t* __restrict__ mln) {
  int row = blockIdx.x, t = threadIdx.x;
  size_t base = (size_t)row * CD;
  f32x4 v = ((const f32x4*)(x + base))[t];
  v += ((const f32x4*)(P + base))[t];
  v += ((const f32x4*)(P + (size_t)8388608 + base))[t];
  v += ((const f32x4*)bo)[t];
  ((f32x4*)(x2 + base))[t] = v;
  float s = v.x + v.y + v.z + v.w;
  float s2 = v.x * v.x + v.y * v.y + v.z * v.z + v.w * v.w;
#pragma unroll
  for (int off = 32; off >= 1; off >>= 1) {
    s += __shfl_xor(s, off);
    s2 += __shfl_xor(s2, off);
  }
  __shared__ float red[8];
  int lane = t & 63, w = t >> 6;
  if (lane == 0) { red[w] = s; red[w + 4] = s2; }
  __syncthreads();
  s = red[0] + red[1] + red[2] + red[3];
  s2 = red[4] + red[5] + red[6] + red[7];
  float mu = s * (1.0f / CD);
  float var = s2 * (1.0f / CD) - mu * mu;
  float rs = rsqrtf(var + 1e-12f);
  f32x4 gg = ((const f32x4*)g)[t];
  f32x4 bb = ((const f32x4*)b)[t];
  u16x4 o;
  o.x = f2bf((v.x - mu) * rs * gg.x + bb.x);
  o.y = f2bf((v.y - mu) * rs * gg.y + bb.y);
  o.z = f2bf((v.z - mu) * rs * gg.z + bb.z);
  o.w = f2bf((v.w - mu) * rs * gg.w + bb.w);
  ((u16x4*)(mln + base))[t] = o;
}

// ---------- final: out = x2 + b2 + P0 + P1 ----------
__global__ void k_final(const float* __restrict__ x2, const float* __restrict__ b2,
                        const float* __restrict__ P, float* __restrict__ out) {
  size_t i = (size_t)blockIdx.x * 256 + threadIdx.x;  // f32x4 index, 2097152 total
  f32x4 v = ((const f32x4*)x2)[i];
  v += ((const f32x4*)P)[i];
  v += ((const f32x4*)(P + 8388608))[i];
  v += ((const f32x4*)b2)[(int)(i & 255)];
  ((f32x4*)out)[i] = v;
}

// ---------- bf16 GEMM: C[M x N] = A[M x lda-mat] * Bt[N x ldb-mat]^T over Klen, fused epi ----------
// 128x128 tile, BK=64, 256 threads (4 waves 2x2), single-buffer 32KB LDS. Proven ~604 TF core.
// Adds: XCD-chunked bijective blockIdx swizzle (T1/m204) + optional split-K (fp32 partials).
enum { EP_AV = 0, EP_ELU1 = 1, EP_GELU = 2, EP_KS = 3 };

template <int EP>
__global__ __launch_bounds__(256, 4) void k_gemm(const ushort_t* __restrict__ A,
                                                 const ushort_t* __restrict__ Bt, int N, int lda,
                                                 int ldb, int Klen, int nbx, int nks,
                                                 const float* __restrict__ bias,
                                                 const float* __restrict__ bias2,
                                                 float* __restrict__ outf,
                                                 ushort_t* __restrict__ outb,
                                                 ushort_t* __restrict__ out2) {
  __shared__ __align__(16) ushort_t sA[128 * 64];
  __shared__ __align__(16) ushort_t sB[128 * 64];
  const int t = threadIdx.x;
  const int lane = t & 63;
  const int w = t >> 6;
  const int wr = w >> 1, wc = w & 1;
  const int lr = lane & 15, lq = lane >> 4;

  // XCD-chunked swizzle: contiguous wg range per XCD (grids are multiples of 8)
  int bid = blockIdx.x;
  int q = gridDim.x >> 3;
  int wg = (bid & 7) * q + (bid >> 3);
  int by = wg / (nbx * nks);
  int rem = wg - by * (nbx * nks);
  int bx = rem / nks;
  int ks = rem - bx * nks;
  const int m0 = by * 128, n0 = bx * 128;
  const int koff = ks * Klen;

  f32x4 acc[4][4];
#pragma unroll
  for (int i = 0; i < 4; ++i)
#pragma unroll
    for (int j = 0; j < 4; ++j) acc[i][j] = f32x4{0.f, 0.f, 0.f, 0.f};

  for (int kt = 0; kt < Klen; kt += 64) {
#pragma unroll
    for (int i = 0; i < 4; ++i) {
      int c = t + i * 256;           // 1024 chunks of 16B per 128x64 tile
      int row = c >> 3;              // 8 chunks per 64-elem row
      int sl = (c & 7) ^ (row & 7);  // pre-swizzled global source, linear LDS dest
      int ldsoff = (w * 64 + i * 256) * 8;  // wave-uniform base (ushort units)
      gload16(A + (size_t)(m0 + row) * lda + koff + kt + sl * 8, sA + ldsoff);
      gload16(Bt + (size_t)(n0 + row) * ldb + koff + kt + sl * 8, sB + ldsoff);
    }
    __syncthreads();
#pragma unroll
    for (int kk = 0; kk < 2; ++kk) {
      int slog = kk * 4 + lq;
      bf16x8 af[4], bfr[4];
#pragma unroll
      for (int mi = 0; mi < 4; ++mi) af[mi] = frag64(sA, wr * 64 + mi * 16 + lr, slog);
#pragma unroll
      for (int ni = 0; ni < 4; ++ni) bfr[ni] = frag64(sB, wc * 64 + ni * 16 + lr, slog);
#pragma unroll
      for (int mi = 0; mi < 4; ++mi)
#pragma unroll
        for (int ni = 0; ni < 4; ++ni)
          acc[mi][ni] =
              __builtin_amdgcn_mfma_f32_16x16x32_bf16(af[mi], bfr[ni], acc[mi][ni], 0, 0, 0);
    }
    __syncthreads();
  }

#pragma unroll
  for (int mi = 0; mi < 4; ++mi) {
#pragma unroll
    for (int ni = 0; ni < 4; ++ni) {
      int col = n0 + wc * 64 + ni * 16 + lr;
#pragma unroll
      for (int r = 0; r < 4; ++r) {
        int row = m0 + wr * 64 + mi * 16 + lq * 4 + r;
        if constexpr (EP == EP_AV) {
          // col in [0,2048): [0,1024) silu->outb(act), [1024,2048) plain->out2(v)
          if (col < 1024) {
            float vv = acc[mi][ni][r] + bias[col];
            outb[(size_t)row * 1024 + col] = f2bf(vv / (1.f + expf(-vv)));
          } else {
            float vv = acc[mi][ni][r] + bias2[col - 1024];
            out2[(size_t)row * 1024 + (col - 1024)] = f2bf(vv);
          }
        } else if constexpr (EP == EP_ELU1) {
          float vv = acc[mi][ni][r] + bias[col];
          outb[(size_t)row * N + col] = f2bf(vv > 0.f ? vv + 1.f : expf(vv));
        } else if constexpr (EP == EP_GELU) {
          float vv = acc[mi][ni][r] + bias[col];
          outb[(size_t)row * N + col] = f2bf(0.5f * vv * (1.f + erff(vv * 0.70710678118654752f)));
        } else {  // EP_KS: fp32 partial, no bias (combiner adds bias + residual)
          outf[(size_t)ks * 8388608 + (size_t)row * N + col] = acc[mi][ni][r];
        }
      }
    }
  }
}

// ---------- attention reduce: per (b,h,lsplit): kv[e][d]=sum_l v[l,e]*k_rope[l,d]; kmean ----------
__global__ __launch_bounds__(256) void k_attn_reduce(const ushort_t* __restrict__ qk,
                                                     const ushort_t* __restrict__ vbf,
                                                     const ushort_t* __restrict__ cosT,
                                                     const ushort_t* __restrict__ sinT,
                                                     float* __restrict__ kvpart,
                                                     float* __restrict__ kmpart) {
  int bh = blockIdx.x >> 2, ls = blockIdx.x & 3;
  int b = bh >> 4, h = bh & 15;
  int t = threadIdx.x, lane = t & 63, w = t >> 6;

  __shared__ float kst[64][68];
  __shared__ __align__(16) ushort_t krT[64 * 64];  // [d][l] swizzled
  __shared__ __align__(16) ushort_t vT[64 * 64];   // [e][l] swizzled
  __shared__ float cst[64][32];
  __shared__ float snt[64][32];
  __shared__ float kmp[4][64];

  float kmacc = 0.f;
  f32x4 acc[4];
#pragma unroll
  for (int i = 0; i < 4; ++i) acc[i] = f32x4{0.f, 0.f, 0.f, 0.f};

  for (int c = ls * 8; c < ls * 8 + 8; ++c) {
    int l0 = c * 64;
    for (int idx = t; idx < 4096; idx += 256) {
      int l = idx >> 6, d = idx & 63;
      size_t grow = (size_t)(b * CL + l0 + l);
      float kvv = bf2f(qk[grow * 2048 + 1024 + h * 64 + d]);
      kst[l][d] = kvv;
      kmacc += kvv;
      ushort_t vv = vbf[grow * CD + h * 64 + d];
      int sl = (l >> 3) ^ (d & 7);
      vT[d * 64 + sl * 8 + (l & 7)] = vv;
    }
    for (int idx = t; idx < 2048; idx += 256) {
      int l = idx >> 5, j = idx & 31;
      size_t p = (size_t)(l0 + l) * 512 + h * 32 + j;
      cst[l][j] = bf2f(cosT[p]);
      snt[l][j] = bf2f(sinT[p]);
    }
    __syncthreads();
    for (int idx = t; idx < 4096; idx += 256) {
      int l = idx >> 6, d = idx & 63, j = d >> 1;
      float cc = cst[l][j], sn = snt[l][j];
      float kr = (d & 1) ? (kst[l][d - 1] * sn + kst[l][d] * cc)
                         : (kst[l][d] * cc - kst[l][d + 1] * sn);
      int sl = (l >> 3) ^ (d & 7);
      krT[d * 64 + sl * 8 + (l & 7)] = f2bf(kr);
    }
    __syncthreads();
#pragma unroll
    for (int kk = 0; kk < 2; ++kk) {
      int slog = kk * 4 + (lane >> 4);
      bf16x8 a = frag64(vT, w * 16 + (lane & 15), slog);  // rows = e
#pragma unroll
      for (int ni = 0; ni < 4; ++ni) {
        bf16x8 bb = frag64(krT, ni * 16 + (lane & 15), slog);  // cols = d
        acc[ni] = __builtin_amdgcn_mfma_f32_16x16x32_bf16(a, bb, acc[ni], 0, 0, 0);
      }
    }
    __syncthreads();
  }
  float* kp = kvpart + ((size_t)(bh * 4 + ls)) * 4096;
#pragma unroll
  for (int ni = 0; ni < 4; ++ni) {
    int d = ni * 16 + (lane & 15);
#pragma unroll
    for (int r = 0; r < 4; ++r) {
      int e = w * 16 + (lane >> 4) * 4 + r;
      kp[e * 64 + d] = acc[ni][r];
    }
  }
  kmp[t >> 6][t & 63] = kmacc;
  __syncthreads();
  if (t < 64) kmpart[(bh * 4 + ls) * 64 + t] = kmp[0][t] + kmp[1][t] + kmp[2][t] + kmp[3][t];
}

// ---------- reduce partials ----------
__global__ void k_kv_reduce(const float* __restrict__ kvpart, const float* __restrict__ kmpart,
                            ushort_t* __restrict__ kvT, float* __restrict__ kmean) {
  int gid = blockIdx.x * 256 + threadIdx.x;  // 64*4096
  int bh = gid >> 12;
  int r = gid & 4095;
  float s = 0.f;
#pragma unroll
  for (int ls = 0; ls < 4; ++ls) s += kvpart[((size_t)(bh * 4 + ls)) * 4096 + r];
  kvT[gid] = f2bf(s);
  if (gid < 64 * 64) {
    int bh2 = gid >> 6, d = gid & 63;
    float m = 0.f;
#pragma unroll
    for (int ls = 0; ls < 4; ++ls) m += kmpart[(bh2 * 4 + ls) * 64 + d];
    kmean[gid] = m;
  }
}

// ---------- attention out + depthwise conv4 + silu + gate: A4 = (attn + silu(conv(v))) * act ----------
__global__ __launch_bounds__(256) void k_attn_out(
    const ushort_t* __restrict__ qk, const ushort_t* __restrict__ kvT,
    const float* __restrict__ kmean, const ushort_t* __restrict__ cosT,
    const ushort_t* __restrict__ sinT, const ushort_t* __restrict__ vbf,
    const ushort_t* __restrict__ act, const float* __restrict__ convw,
    const float* __restrict__ convb, ushort_t* __restrict__ A4) {
  int bid = blockIdx.x;  // bh*32 + lt
  int bh = bid >> 5, lt = bid & 31;
  int b = bh >> 4, h = bh & 15;
  int l0 = lt * 64;
  int t = threadIdx.x, lane = t & 63, w = t >> 6;

  __shared__ float qst[64][68];
  __shared__ __align__(16) ushort_t qrT[64 * 64];
  __shared__ __align__(16) ushort_t kvs[64 * 64];
  __shared__ float cst[64][32];
  __shared__ float snt[64][32];
  __shared__ float kms[64];
  __shared__ float zrow[64];

  if (t < 64) kms[t] = kmean[bh * 64 + t];
  for (int idx = t; idx < 4096; idx += 256) {
    int l = idx >> 6, d = idx & 63;
    qst[l][d] = bf2f(qk[(size_t)(b * CL + l0 + l) * 2048 + h * 64 + d]);
    ushort_t kvv = kvT[(size_t)bh * 4096 + idx];
    int e = idx >> 6, dd = idx & 63;
    int sl = (dd >> 3) ^ (e & 7);
    kvs[e * 64 + sl * 8 + (dd & 7)] = kvv;
  }
  for (int idx = t; idx < 2048; idx += 256) {
    int l = idx >> 5, j = idx & 31;
    size_t p = (size_t)(l0 + l) * 512 + h * 32 + j;
    cst[l][j] = bf2f(cosT[p]);
    snt[l][j] = bf2f(sinT[p]);
  }
  __syncthreads();
  for (int idx = t; idx < 4096; idx += 256) {
    int l = idx >> 6, d = idx & 63, j = d >> 1;
    float cc = cst[l][j], sn = snt[l][j];
    float qr = (d & 1) ? (qst[l][d - 1] * sn + qst[l][d] * cc)
                       : (qst[l][d] * cc - qst[l][d + 1] * sn);
    int sl = (d >> 3) ^ (l & 7);
    qrT[l * 64 + sl * 8 + (d & 7)] = f2bf(qr);
  }
  if (t < 64) {
    float dot = 0.f;
#pragma unroll
    for (int d = 0; d < 64; ++d) dot += qst[t][d] * kms[d];
    zrow[t] = 1.0f / (dot * (1.0f / (float)CL) + 1e-6f);
  }
  __syncthreads();
  f32x4 acc[4];
#pragma unroll
  for (int i = 0; i < 4; ++i) acc[i] = f32x4{0.f, 0.f, 0.f, 0.f};
#pragma unroll
  for (int kk = 0; kk < 2; ++kk) {
    int slog = kk * 4 + (lane >> 4);
    bf16x8 a = frag64(qrT, w * 16 + (lane & 15), slog);
#pragma unroll
    for (int ni = 0; ni < 4; ++ni) {
      bf16x8 bb = frag64(kvs, ni * 16 + (lane & 15), slog);
      acc[ni] = __builtin_amdgcn_mfma_f32_16x16x32_bf16(a, bb, acc[ni], 0, 0, 0);
    }
  }
#pragma unroll
  for (int ni = 0; ni < 4; ++ni) {
    int e = ni * 16 + (lane & 15);
    int dcol = h * 64 + e;
#pragma unroll
    for (int r = 0; r < 4; ++r) {
      int l = w * 16 + (lane >> 4) * 4 + r;
      int lg = l0 + l;
      size_t row = (size_t)(b * CL + lg);
      float val = acc[ni][r] * zrow[l] * (1.0f / (float)CL);
      // depthwise causal conv k=4 + silu
      float cv = convb[dcol];
#pragma unroll
      for (int tt = 0; tt < 4; ++tt) {
        if (lg - 3 + tt >= 0) cv += bf2f(vbf[(row - 3 + tt) * CD + dcol]) * convw[dcol * 4 + tt];
      }
      cv = cv / (1.f + expf(-cv));
      float a4 = (val + cv) * bf2f(act[row * CD + dcol]);
      A4[row * CD + dcol] = f2bf(a4);
    }
  }
}

// ---------- launch ----------
extern "C" void kernel_launch(void* const* d_in, const int* in_sizes, int n_in, void* d_out,
                              int out_size, void* d_ws, size_t ws_size, hipStream_t stream) {
  const float* x = (const float*)d_in[0];
  const float* ln1_g = (const float*)d_in[1];
  const float* ln1_b = (const float*)d_in[2];
  const float* ln2_g = (const float*)d_in[3];
  const float* ln2_b = (const float*)d_in[4];
  const float* W_act = (const float*)d_in[5];
  const float* b_act = (const float*)d_in[6];
  const float* W_in = (const float*)d_in[7];
  const float* b_in = (const float*)d_in[8];
  const float* W_qk = (const float*)d_in[9];
  const float* b_qk = (const float*)d_in[10];
  const float* conv_w = (const float*)d_in[11];
  const float* conv_b = (const float*)d_in[12];
  const float* W_out = (const float*)d_in[13];
  const float* b_out = (const float*)d_in[14];
  const float* W1 = (const float*)d_in[15];
  const float* b1 = (const float*)d_in[16];
  const float* W2 = (const float*)d_in[17];
  const float* b2 = (const float*)d_in[18];
  float* out = (float*)d_out;

  // ---- 192MB workspace plan (exact map proven in round 4) ----
  char* w = (char*)d_ws;
  const size_t MB = 1024 * 1024;
  // [0,16)MB: prep/attn-phase data; mln aliases after (all dead by addln)
  ushort_t* cosT = (ushort_t*)(w + 0 * MB);           // 2MB, last read attn_out
  ushort_t* sinT = (ushort_t*)(w + 2 * MB);           // 2MB, last read attn_out
  ushort_t* WabT = (ushort_t*)(w + 4 * MB);           // 4MB, last read G1
  ushort_t* WqkT = (ushort_t*)(w + 8 * MB);           // 4MB, last read G2
  ushort_t* WoutT = (ushort_t*)(w + 12 * MB);         // 2MB, last read G3
  ushort_t* kvTb = (ushort_t*)(w + 14 * MB);          // 0.5MB, last read attn_out
  float* kmean = (float*)(w + 14 * MB + 512 * 1024);  // 16KB, last read attn_out
  float* kmpart = (float*)(w + 14 * MB + 640 * 1024); // 64KB, last read kv_reduce
  ushort_t* mln = (ushort_t*)(w + 0 * MB);            // 16MB ALIAS, written addln (after G3)
  // [16,32): MLP weights
  ushort_t* W1T = (ushort_t*)(w + 16 * MB);           // 8MB, last read G4
  ushort_t* W2T = (ushort_t*)(w + 24 * MB);           // 8MB, last read G5
  // [32,96): hln/qkb/actb dead after attn_out -> Gb aliases (written G4)
  ushort_t* hln = (ushort_t*)(w + 32 * MB);           // 16MB, last read G1
  ushort_t* qkb = (ushort_t*)(w + 48 * MB);           // 32MB, last read attn_out
  ushort_t* actb = (ushort_t*)(w + 80 * MB);          // 16MB, last read attn_out
  ushort_t* Gb = (ushort_t*)(w + 32 * MB);            // 64MB ALIAS, written G4
  // [96,128): vb + A4 (kvpart aliases A4 slot) -> x2 aliases after G3
  ushort_t* vb = (ushort_t*)(w + 96 * MB);            // 16MB, last read attn_out
  ushort_t* A4 = (ushort_t*)(w + 112 * MB);           // 16MB, written attn_out, read G3
  float* kvpart = (float*)(w + 112 * MB);             // 4MB ALIAS, dead after kv_reduce
  float* x2 = (float*)(w + 96 * MB);                  // 32MB ALIAS, written addln, read final
  // [128,192): split-K fp32 partials (G3->addln, then G5->final)
  float* PP = (float*)(w + 128 * MB);                 // 64MB

  (void)in_sizes; (void)n_in; (void)out_size; (void)ws_size;

  // 1. prep: rope tables + all 6 weight transposes
  k_prep<<<17408, 256, 0, stream>>>(W_act, W_in, W_qk, W_out, W1, W2, WabT, WqkT, WoutT, W1T, W2T,
                                    cosT, sinT);
  // 2. LN1
  k_layernorm<<<CM, 256, 0, stream>>>(x, ln1_g, ln1_b, hln);
  // 3. G1: [act | v] = hln @ [WactT;WinT]^T, N=2048 (grid 16x64 = 1024)
  k_gemm<EP_AV><<<1024, 256, 0, stream>>>(hln, WabT, 2048, 1024, 1024, 1024, 16, 1, b_act, b_in,
                                          nullptr, actb, vb);
  // 4. G2: qk = elu(v @ WqkT^T + b_qk)+1, N=2048
  k_gemm<EP_ELU1><<<1024, 256, 0, stream>>>(vb, WqkT, 2048, 1024, 1024, 1024, 16, 1, b_qk, nullptr,
                                            nullptr, qkb, nullptr);
  // 5-7. attention
  k_attn_reduce<<<256, 256, 0, stream>>>(qkb, vb, cosT, sinT, kvpart, kmpart);
  k_kv_reduce<<<1024, 256, 0, stream>>>(kvpart, kmpart, kvTb, kmean);
  k_attn_out<<<2048, 256, 0, stream>>>(qkb, kvTb, kmean, cosT, sinT, vb, actb, conv_w, conv_b, A4);
  // 8. G3: PP[ks] = A4 @ WoutT^T partials, N=1024, split-K=2 (grid 8x64x2 = 1024)
  k_gemm<EP_KS><<<1024, 256, 0, stream>>>(A4, WoutT, 1024, 1024, 1024, 512, 8, 2, nullptr, nullptr,
                                          PP, nullptr, nullptr);
  // 9. x2 = x + b_out + P0 + P1; mln = LN2(x2)
  k_addln<<<CM, 256, 0, stream>>>(x, b_out, PP, ln2_g, ln2_b, x2, mln);
  // 10. G4: Gb = gelu(mln @ W1T^T + b1), N=4096 (grid 32x64 = 2048)
  k_gemm<EP_GELU><<<2048, 256, 0, stream>>>(mln, W1T, 4096, 1024, 1024, 1024, 32, 1, b1, nullptr,
                                            nullptr, Gb, nullptr);
  // 11. G5: PP[ks] = Gb @ W2T^T partials, N=1024, K=4096 split-K=2 (grid 8x64x2 = 1024)
  k_gemm<EP_KS><<<1024, 256, 0, stream>>>(Gb, W2T, 1024, 4096, 4096, 2048, 8, 2, nullptr, nullptr,
                                          PP, nullptr, nullptr);
  // 12. out = x2 + b2 + P0 + P1
  k_final<<<8192, 256, 0, stream>>>(x2, b2, PP, out);
}

// Round 7
// 484.481 us; speedup vs baseline: 1.0598x; 1.0598x over previous
//
#include <hip/hip_runtime.h>
#include <math.h>

typedef unsigned short ushort_t;
typedef __attribute__((ext_vector_type(4))) float f32x4;
typedef __attribute__((ext_vector_type(8))) __bf16 bf16x8;
typedef __attribute__((ext_vector_type(8))) unsigned short u16x8;
typedef __attribute__((ext_vector_type(4))) unsigned short u16x4;

#define DEV __device__ __forceinline__

// B=4, L=2048, D=1024, H=16, HD=64, M=B*L=8192
#define CB 4
#define CL 2048
#define CD 1024
#define CM 8192

DEV float bf2f(ushort_t u) {
  unsigned int x = ((unsigned int)u) << 16;
  return __builtin_bit_cast(float, x);
}
DEV ushort_t f2bf(float f) {
  unsigned int u = __builtin_bit_cast(unsigned int, f);
  u += 0x7FFFu + ((u >> 16) & 1u);
  return (ushort_t)(u >> 16);
}
DEV void gload16(const void* g, void* l) {
  __builtin_amdgcn_global_load_lds((const __attribute__((address_space(1))) void*)g,
                                   (__attribute__((address_space(3))) void*)l, 16, 0, 0);
}
// read one 16B MFMA fragment from a [rows][64] ushort LDS tile with XOR(row&7) slot swizzle
DEV bf16x8 frag64(const ushort_t* s, int row, int slog) {
  int sl = slog ^ (row & 7);
  return __builtin_bit_cast(bf16x8, *reinterpret_cast<const u16x8*>(s + row * 64 + sl * 8));
}

// ---------- prep: all weight transposes + rope tables in ONE dispatch ----------
DEV void tr_tile(const float* __restrict__ src, ushort_t* __restrict__ dst, int R, int C, int bx,
                 int by, int t) {
  __shared__ float tile[32][33];
  int c0 = bx * 32, r0 = by * 32;
  int tx = t & 31, ty = t >> 5;  // 32 x 8
#pragma unroll
  for (int i = 0; i < 32; i += 8) tile[ty + i][tx] = src[(size_t)(r0 + ty + i) * C + c0 + tx];
  __syncthreads();
#pragma unroll
  for (int i = 0; i < 32; i += 8) dst[(size_t)(c0 + ty + i) * R + r0 + tx] = f2bf(tile[tx][ty + i]);
}

__global__ __launch_bounds__(256) void k_prep(const float* __restrict__ W_act,
                                              const float* __restrict__ W_in,
                                              const float* __restrict__ W_qk,
                                              const float* __restrict__ W_out,
                                              const float* __restrict__ W1,
                                              const float* __restrict__ W2,
                                              ushort_t* __restrict__ WabT,
                                              ushort_t* __restrict__ WqkT,
                                              ushort_t* __restrict__ WoutT,
                                              ushort_t* __restrict__ W1T,
                                              ushort_t* __restrict__ W2T,
                                              ushort_t* __restrict__ cosT,
                                              ushort_t* __restrict__ sinT) {
  int bid = blockIdx.x, t = threadIdx.x;
  if (bid < 4096) {  // rope tables: L*512 entries
    int idx = bid * 256 + t;
    int l = idx >> 9, j = idx & 511;
    float theta = exp2f(-(float)j * (13.2877123795494f / 512.0f));
    float ang = (float)l * theta;
    float s, c;
    sincosf(ang, &s, &c);
    cosT[idx] = f2bf(c);
    sinT[idx] = f2bf(s);
  } else if (bid < 5120) {
    int lo = bid - 4096;
    tr_tile(W_act, WabT, 1024, 1024, lo & 31, lo >> 5, t);
  } else if (bid < 6144) {
    int lo = bid - 5120;
    tr_tile(W_in, WabT + (size_t)1024 * 1024, 1024, 1024, lo & 31, lo >> 5, t);
  } else if (bid < 8192) {
    int lo = bid - 6144;
    tr_tile(W_qk, WqkT, 1024, 2048, lo & 63, lo >> 6, t);
  } else if (bid < 9216) {
    int lo = bid - 8192;
    tr_tile(W_out, WoutT, 1024, 1024, lo & 31, lo >> 5, t);
  } else if (bid < 13312) {
    int lo = bid - 9216;
    tr_tile(W1, W1T, 1024, 4096, lo & 127, lo >> 7, t);
  } else {
    int lo = bid - 13312;
    tr_tile(W2, W2T, 4096, 1024, lo & 31, lo >> 5, t);
  }
}

// ---------- layernorm: fp32 in -> bf16 out ----------
__global__ __launch_bounds__(256) void k_layernorm(const float* __restrict__ x,
                                                   const float* __restrict__ g,
                                                   const float* __restrict__ b,
                                                   ushort_t* __restrict__ out) {
  int row = blockIdx.x, t = threadIdx.x;
  const float* xr = x + (size_t)row * CD;
  f32x4 v = ((const f32x4*)xr)[t];
  float s = v.x + v.y + v.z + v.w;
  float s2 = v.x * v.x + v.y * v.y + v.z * v.z + v.w * v.w;
#pragma unroll
  for (int off = 32; off >= 1; off >>= 1) {
    s += __shfl_xor(s, off);
    s2 += __shfl_xor(s2, off);
  }
  __shared__ float red[8];
  int lane = t & 63, w = t >> 6;
  if (lane == 0) { red[w] = s; red[w + 4] = s2; }
  __syncthreads();
  s = red[0] + red[1] + red[2] + red[3];
  s2 = red[4] + red[5] + red[6] + red[7];
  float mu = s * (1.0f / CD);
  float var = s2 * (1.0f / CD) - mu * mu;
  float rs = rsqrtf(var + 1e-12f);
  f32x4 gg = ((const f32x4*)g)[t];
  f32x4 bb = ((const f32x4*)b)[t];
  u16x4 o;
  o.x = f2bf((v.x - mu) * rs * gg.x + bb.x);
  o.y = f2bf((v.y - mu) * rs * gg.y + bb.y);
  o.z = f2bf((v.z - mu) * rs * gg.z + bb.z);
  o.w = f2bf((v.w - mu) * rs * gg.w + bb.w);
  ((u16x4*)(out + (size_t)row * CD))[t] = o;
}

// ---------- bf16 GEMM: C[M x N] = A[M x K] * Bt[N x K]^T, fused epilogues ----------
// 128x128 tile, BK=64, 256 threads (4 waves 2x2), single-buffer 32KB LDS. Proven ~604 TF core.
// Block->tile map: 4x4 supergroups (consecutive bids fill a 512x512 output region) to cut the
// chip-wide live A/B panel working set ~4x. No XCD transform (round-6 chunking regressed).
enum { EP_AV = 0, EP_ELU1 = 1, EP_GELU = 2, EP_ADDX = 3 };

template <int EP>
__global__ __launch_bounds__(256, 4) void k_gemm(const ushort_t* __restrict__ A,
                                                 const ushort_t* __restrict__ Bt, int N, int K,
                                                 int nbx,
                                                 const float* __restrict__ bias,
                                                 const float* __restrict__ bias2,
                                                 const float* __restrict__ addf,
                                                 float* __restrict__ outf,
                                                 ushort_t* __restrict__ outb,
                                                 ushort_t* __restrict__ out2) {
  __shared__ __align__(16) ushort_t sA[128 * 64];
  __shared__ __align__(16) ushort_t sB[128 * 64];
  const int t = threadIdx.x;
  const int lane = t & 63;
  const int w = t >> 6;
  const int wr = w >> 1, wc = w & 1;
  const int lr = lane & 15, lq = lane >> 4;

  // 4x4 supergroup decomposition (nbx and nby=64 are multiples of 4)
  int bid = blockIdx.x;
  int sg = bid >> 4, inner = bid & 15;
  int sgxc = nbx >> 2;
  int sgy = sg / sgxc, sgx = sg - sgy * sgxc;
  int by = sgy * 4 + (inner >> 2);
  int bx = sgx * 4 + (inner & 3);
  const int m0 = by * 128, n0 = bx * 128;

  f32x4 acc[4][4];
#pragma unroll
  for (int i = 0; i < 4; ++i)
#pragma unroll
    for (int j = 0; j < 4; ++j) acc[i][j] = f32x4{0.f, 0.f, 0.f, 0.f};

  for (int kt = 0; kt < K; kt += 64) {
#pragma unroll
    for (int i = 0; i < 4; ++i) {
      int c = t + i * 256;           // 1024 chunks of 16B per 128x64 tile
      int row = c >> 3;              // 8 chunks per 64-elem row
      int sl = (c & 7) ^ (row & 7);  // pre-swizzled global source, linear LDS dest
      int ldsoff = (w * 64 + i * 256) * 8;  // wave-uniform base (ushort units)
      gload16(A + (size_t)(m0 + row) * K + kt + sl * 8, sA + ldsoff);
      gload16(Bt + (size_t)(n0 + row) * K + kt + sl * 8, sB + ldsoff);
    }
    __syncthreads();
#pragma unroll
    for (int kk = 0; kk < 2; ++kk) {
      int slog = kk * 4 + lq;
      bf16x8 af[4], bfr[4];
#pragma unroll
      for (int mi = 0; mi < 4; ++mi) af[mi] = frag64(sA, wr * 64 + mi * 16 + lr, slog);
#pragma unroll
      for (int ni = 0; ni < 4; ++ni) bfr[ni] = frag64(sB, wc * 64 + ni * 16 + lr, slog);
#pragma unroll
      for (int mi = 0; mi < 4; ++mi)
#pragma unroll
        for (int ni = 0; ni < 4; ++ni)
          acc[mi][ni] =
              __builtin_amdgcn_mfma_f32_16x16x32_bf16(af[mi], bfr[ni], acc[mi][ni], 0, 0, 0);
    }
    __syncthreads();
  }

#pragma unroll
  for (int mi = 0; mi < 4; ++mi) {
#pragma unroll
    for (int ni = 0; ni < 4; ++ni) {
      int col = n0 + wc * 64 + ni * 16 + lr;
#pragma unroll
      for (int r = 0; r < 4; ++r) {
        int row = m0 + wr * 64 + mi * 16 + lq * 4 + r;
        if constexpr (EP == EP_AV) {
          // col in [0,2048): [0,1024) silu->outb(act), [1024,2048) plain->out2(v)
          if (col < 1024) {
            float vv = acc[mi][ni][r] + bias[col];
            outb[(size_t)row * 1024 + col] = f2bf(vv / (1.f + expf(-vv)));
          } else {
            float vv = acc[mi][ni][r] + bias2[col - 1024];
            out2[(size_t)row * 1024 + (col - 1024)] = f2bf(vv);
          }
        } else if constexpr (EP == EP_ELU1) {
          float vv = acc[mi][ni][r] + bias[col];
          outb[(size_t)row * N + col] = f2bf(vv > 0.f ? vv + 1.f : expf(vv));
        } else if constexpr (EP == EP_GELU) {
          float vv = acc[mi][ni][r] + bias[col];
          outb[(size_t)row * N + col] = f2bf(0.5f * vv * (1.f + erff(vv * 0.70710678118654752f)));
        } else {  // EP_ADDX: fp32 out = addf + gemm + bias
          size_t idx = (size_t)row * N + col;
          outf[idx] = addf[idx] + acc[mi][ni][r] + bias[col];
        }
      }
    }
  }
}

// ---------- attention reduce: per (b,h,lsplit): kv[e][d]=sum_l v[l,e]*k_rope[l,d]; kmean ----------
__global__ __launch_bounds__(256) void k_attn_reduce(const ushort_t* __restrict__ qk,
                                                     const ushort_t* __restrict__ vbf,
                                                     const ushort_t* __restrict__ cosT,
                                                     const ushort_t* __restrict__ sinT,
                                                     float* __restrict__ kvpart,
                                                     float* __restrict__ kmpart) {
  int bh = blockIdx.x >> 2, ls = blockIdx.x & 3;
  int b = bh >> 4, h = bh & 15;
  int t = threadIdx.x, lane = t & 63, w = t >> 6;

  __shared__ float kst[64][68];
  __shared__ __align__(16) ushort_t krT[64 * 64];  // [d][l] swizzled
  __shared__ __align__(16) ushort_t vT[64 * 64];   // [e][l] swizzled
  __shared__ float cst[64][32];
  __shared__ float snt[64][32];
  __shared__ float kmp[4][64];

  float kmacc = 0.f;
  f32x4 acc[4];
#pragma unroll
  for (int i = 0; i < 4; ++i) acc[i] = f32x4{0.f, 0.f, 0.f, 0.f};

  for (int c = ls * 8; c < ls * 8 + 8; ++c) {
    int l0 = c * 64;
    for (int idx = t; idx < 4096; idx += 256) {
      int l = idx >> 6, d = idx & 63;
      size_t grow = (size_t)(b * CL + l0 + l);
      float kvv = bf2f(qk[grow * 2048 + 1024 + h * 64 + d]);
      kst[l][d] = kvv;
      kmacc += kvv;
      ushort_t vv = vbf[grow * CD + h * 64 + d];
      int sl = (l >> 3) ^ (d & 7);
      vT[d * 64 + sl * 8 + (l & 7)] = vv;
    }
    for (int idx = t; idx < 2048; idx += 256) {
      int l = idx >> 5, j = idx & 31;
      size_t p = (size_t)(l0 + l) * 512 + h * 32 + j;
      cst[l][j] = bf2f(cosT[p]);
      snt[l][j] = bf2f(sinT[p]);
    }
    __syncthreads();
    for (int idx = t; idx < 4096; idx += 256) {
      int l = idx >> 6, d = idx & 63, j = d >> 1;
      float cc = cst[l][j], sn = snt[l][j];
      float kr = (d & 1) ? (kst[l][d - 1] * sn + kst[l][d] * cc)
                         : (kst[l][d] * cc - kst[l][d + 1] * sn);
      int sl = (l >> 3) ^ (d & 7);
      krT[d * 64 + sl * 8 + (l & 7)] = f2bf(kr);
    }
    __syncthreads();
#pragma unroll
    for (int kk = 0; kk < 2; ++kk) {
      int slog = kk * 4 + (lane >> 4);
      bf16x8 a = frag64(vT, w * 16 + (lane & 15), slog);  // rows = e
#pragma unroll
      for (int ni = 0; ni < 4; ++ni) {
        bf16x8 bb = frag64(krT, ni * 16 + (lane & 15), slog);  // cols = d
        acc[ni] = __builtin_amdgcn_mfma_f32_16x16x32_bf16(a, bb, acc[ni], 0, 0, 0);
      }
    }
    __syncthreads();
  }
  float* kp = kvpart + ((size_t)(bh * 4 + ls)) * 4096;
#pragma unroll
  for (int ni = 0; ni < 4; ++ni) {
    int d = ni * 16 + (lane & 15);
#pragma unroll
    for (int r = 0; r < 4; ++r) {
      int e = w * 16 + (lane >> 4) * 4 + r;
      kp[e * 64 + d] = acc[ni][r];
    }
  }
  kmp[t >> 6][t & 63] = kmacc;
  __syncthreads();
  if (t < 64) kmpart[(bh * 4 + ls) * 64 + t] = kmp[0][t] + kmp[1][t] + kmp[2][t] + kmp[3][t];
}

// ---------- reduce partials ----------
__global__ void k_kv_reduce(const float* __restrict__ kvpart, const float* __restrict__ kmpart,
                            ushort_t* __restrict__ kvT, float* __restrict__ kmean) {
  int gid = blockIdx.x * 256 + threadIdx.x;  // 64*4096
  int bh = gid >> 12;
  int r = gid & 4095;
  float s = 0.f;
#pragma unroll
  for (int ls = 0; ls < 4; ++ls) s += kvpart[((size_t)(bh * 4 + ls)) * 4096 + r];
  kvT[gid] = f2bf(s);
  if (gid < 64 * 64) {
    int bh2 = gid >> 6, d = gid & 63;
    float m = 0.f;
#pragma unroll
    for (int ls = 0; ls < 4; ++ls) m += kmpart[(bh2 * 4 + ls) * 64 + d];
    kmean[gid] = m;
  }
}

// ---------- attention out + depthwise conv4 + silu + gate: A4 = (attn + silu(conv(v))) * act ----------
__global__ __launch_bounds__(256) void k_attn_out(
    const ushort_t* __restrict__ qk, const ushort_t* __restrict__ kvT,
    const float* __restrict__ kmean, const ushort_t* __restrict__ cosT,
    const ushort_t* __restrict__ sinT, const ushort_t* __restrict__ vbf,
    const ushort_t* __restrict__ act, const float* __restrict__ convw,
    const float* __restrict__ convb, ushort_t* __restrict__ A4) {
  int bid = blockIdx.x;  // bh*32 + lt
  int bh = bid >> 5, lt = bid & 31;
  int b = bh >> 4, h = bh & 15;
  int l0 = lt * 64;
  int t = threadIdx.x, lane = t & 63, w = t >> 6;

  __shared__ float qst[64][68];
  __shared__ __align__(16) ushort_t qrT[64 * 64];
  __shared__ __align__(16) ushort_t kvs[64 * 64];
  __shared__ float cst[64][32];
  __shared__ float snt[64][32];
  __shared__ float kms[64];
  __shared__ float zrow[64];

  if (t < 64) kms[t] = kmean[bh * 64 + t];
  for (int idx = t; idx < 4096; idx += 256) {
    int l = idx >> 6, d = idx & 63;
    qst[l][d] = bf2f(qk[(size_t)(b * CL + l0 + l) * 2048 + h * 64 + d]);
    ushort_t kvv = kvT[(size_t)bh * 4096 + idx];
    int e = idx >> 6, dd = idx & 63;
    int sl = (dd >> 3) ^ (e & 7);
    kvs[e * 64 + sl * 8 + (dd & 7)] = kvv;
  }
  for (int idx = t; idx < 2048; idx += 256) {
    int l = idx >> 5, j = idx & 31;
    size_t p = (size_t)(l0 + l) * 512 + h * 32 + j;
    cst[l][j] = bf2f(cosT[p]);
    snt[l][j] = bf2f(sinT[p]);
  }
  __syncthreads();
  for (int idx = t; idx < 4096; idx += 256) {
    int l = idx >> 6, d = idx & 63, j = d >> 1;
    float cc = cst[l][j], sn = snt[l][j];
    float qr = (d & 1) ? (qst[l][d - 1] * sn + qst[l][d] * cc)
                       : (qst[l][d] * cc - qst[l][d + 1] * sn);
    int sl = (d >> 3) ^ (l & 7);
    qrT[l * 64 + sl * 8 + (d & 7)] = f2bf(qr);
  }
  if (t < 64) {
    float dot = 0.f;
#pragma unroll
    for (int d = 0; d < 64; ++d) dot += qst[t][d] * kms[d];
    zrow[t] = 1.0f / (dot * (1.0f / (float)CL) + 1e-6f);
  }
  __syncthreads();
  f32x4 acc[4];
#pragma unroll
  for (int i = 0; i < 4; ++i) acc[i] = f32x4{0.f, 0.f, 0.f, 0.f};
#pragma unroll
  for (int kk = 0; kk < 2; ++kk) {
    int slog = kk * 4 + (lane >> 4);
    bf16x8 a = frag64(qrT, w * 16 + (lane & 15), slog);
#pragma unroll
    for (int ni = 0; ni < 4; ++ni) {
      bf16x8 bb = frag64(kvs, ni * 16 + (lane & 15), slog);
      acc[ni] = __builtin_amdgcn_mfma_f32_16x16x32_bf16(a, bb, acc[ni], 0, 0, 0);
    }
  }
#pragma unroll
  for (int ni = 0; ni < 4; ++ni) {
    int e = ni * 16 + (lane & 15);
    int dcol = h * 64 + e;
#pragma unroll
    for (int r = 0; r < 4; ++r) {
      int l = w * 16 + (lane >> 4) * 4 + r;
      int lg = l0 + l;
      size_t row = (size_t)(b * CL + lg);
      float val = acc[ni][r] * zrow[l] * (1.0f / (float)CL);
      // depthwise causal conv k=4 + silu
      float cv = convb[dcol];
#pragma unroll
      for (int tt = 0; tt < 4; ++tt) {
        if (lg - 3 + tt >= 0) cv += bf2f(vbf[(row - 3 + tt) * CD + dcol]) * convw[dcol * 4 + tt];
      }
      cv = cv / (1.f + expf(-cv));
      float a4 = (val + cv) * bf2f(act[row * CD + dcol]);
      A4[row * CD + dcol] = f2bf(a4);
    }
  }
}

// ---------- launch ----------
extern "C" void kernel_launch(void* const* d_in, const int* in_sizes, int n_in, void* d_out,
                              int out_size, void* d_ws, size_t ws_size, hipStream_t stream) {
  const float* x = (const float*)d_in[0];
  const float* ln1_g = (const float*)d_in[1];
  const float* ln1_b = (const float*)d_in[2];
  const float* ln2_g = (const float*)d_in[3];
  const float* ln2_b = (const float*)d_in[4];
  const float* W_act = (const float*)d_in[5];
  const float* b_act = (const float*)d_in[6];
  const float* W_in = (const float*)d_in[7];
  const float* b_in = (const float*)d_in[8];
  const float* W_qk = (const float*)d_in[9];
  const float* b_qk = (const float*)d_in[10];
  const float* conv_w = (const float*)d_in[11];
  const float* conv_b = (const float*)d_in[12];
  const float* W_out = (const float*)d_in[13];
  const float* b_out = (const float*)d_in[14];
  const float* W1 = (const float*)d_in[15];
  const float* b1 = (const float*)d_in[16];
  const float* W2 = (const float*)d_in[17];
  const float* b2 = (const float*)d_in[18];
  float* out = (float*)d_out;

  // ---- 160MB workspace plan (round-5 map, proven) ----
  char* w = (char*)d_ws;
  const size_t MB = 1024 * 1024;
  // [0,16)MB: prep/attn-phase data; mln aliases after (all dead by LN2)
  ushort_t* cosT = (ushort_t*)(w + 0 * MB);           // 2MB, last read attn_out
  ushort_t* sinT = (ushort_t*)(w + 2 * MB);           // 2MB, last read attn_out
  ushort_t* WabT = (ushort_t*)(w + 4 * MB);           // 4MB, last read G1
  ushort_t* WqkT = (ushort_t*)(w + 8 * MB);           // 4MB, last read G2
  ushort_t* WoutT = (ushort_t*)(w + 12 * MB);         // 2MB, last read G3
  ushort_t* kvTb = (ushort_t*)(w + 14 * MB);          // 0.5MB, last read attn_out
  float* kmean = (float*)(w + 14 * MB + 512 * 1024);  // 16KB, last read attn_out
  float* kmpart = (float*)(w + 14 * MB + 640 * 1024); // 64KB, last read kv_reduce
  ushort_t* mln = (ushort_t*)(w + 0 * MB);            // 16MB ALIAS, written LN2 (after G3)
  // [16,32): MLP weights
  ushort_t* W1T = (ushort_t*)(w + 16 * MB);           // 8MB, last read G4
  ushort_t* W2T = (ushort_t*)(w + 24 * MB);           // 8MB, last read G5
  // [32,96): hln/qkb/actb dead after attn_out -> Gb aliases (written G4)
  ushort_t* hln = (ushort_t*)(w + 32 * MB);           // 16MB, last read G1
  ushort_t* qkb = (ushort_t*)(w + 48 * MB);           // 32MB, last read attn_out
  ushort_t* actb = (ushort_t*)(w + 80 * MB);          // 16MB, last read attn_out
  ushort_t* Gb = (ushort_t*)(w + 32 * MB);            // 64MB ALIAS, written G4
  // [96,128): vb + A4; kvpart aliases A4 slot (dead before attn_out writes A4)
  ushort_t* vb = (ushort_t*)(w + 96 * MB);            // 16MB, last read attn_out
  ushort_t* A4 = (ushort_t*)(w + 112 * MB);           // 16MB, written attn_out, read G3
  float* kvpart = (float*)(w + 112 * MB);             // 4MB ALIAS, dead after kv_reduce
  // [128,160): x2 fp32 (separate from A4 -- G3 reads A4 while writing x2)
  float* x2 = (float*)(w + 128 * MB);                 // 32MB, written G3, read LN2 + G5

  (void)in_sizes; (void)n_in; (void)out_size; (void)ws_size;

  // 1. prep: rope tables + all 6 weight transposes
  k_prep<<<17408, 256, 0, stream>>>(W_act, W_in, W_qk, W_out, W1, W2, WabT, WqkT, WoutT, W1T, W2T,
                                    cosT, sinT);
  // 2. LN1
  k_layernorm<<<CM, 256, 0, stream>>>(x, ln1_g, ln1_b, hln);
  // 3. G1: [act | v] = hln @ [WactT;WinT]^T, N=2048 (nbx=16, grid 1024)
  k_gemm<EP_AV><<<1024, 256, 0, stream>>>(hln, WabT, 2048, 1024, 16, b_act, b_in, nullptr,
                                          nullptr, actb, vb);
  // 4. G2: qk = elu(v @ WqkT^T + b_qk)+1, N=2048
  k_gemm<EP_ELU1><<<1024, 256, 0, stream>>>(vb, WqkT, 2048, 1024, 16, b_qk, nullptr, nullptr,
                                            nullptr, qkb, nullptr);
  // 5-7. attention
  k_attn_reduce<<<256, 256, 0, stream>>>(qkb, vb, cosT, sinT, kvpart, kmpart);
  k_kv_reduce<<<1024, 256, 0, stream>>>(kvpart, kmpart, kvTb, kmean);
  k_attn_out<<<2048, 256, 0, stream>>>(qkb, kvTb, kmean, cosT, sinT, vb, actb, conv_w, conv_b, A4);
  // 8. G3: x2 = x + A4 @ WoutT^T + b_out (fp32), nbx=8, grid 512
  k_gemm<EP_ADDX><<<512, 256, 0, stream>>>(A4, WoutT, 1024, 1024, 8, b_out, nullptr, x, x2,
                                           nullptr, nullptr);
  // 9. LN2
  k_layernorm<<<CM, 256, 0, stream>>>(x2, ln2_g, ln2_b, mln);
  // 10. G4: Gb = gelu(mln @ W1T^T + b1), N=4096, nbx=32, grid 2048
  k_gemm<EP_GELU><<<2048, 256, 0, stream>>>(mln, W1T, 4096, 1024, 32, b1, nullptr, nullptr,
                                            nullptr, Gb, nullptr);
  // 11. G5: out = x2 + Gb @ W2T^T + b2, N=1024, K=4096, nbx=8, grid 512
  k_gemm<EP_ADDX><<<512, 256, 0, stream>>>(Gb, W2T, 1024, 4096, 8, b2, nullptr, x2, out,
                                           nullptr, nullptr);
}

// Round 8
// 448.583 us; speedup vs baseline: 1.1447x; 1.0800x over previous
//
#include <hip/hip_runtime.h>
#include <math.h>

typedef unsigned short ushort_t;
typedef __attribute__((ext_vector_type(4))) float f32x4;
typedef __attribute__((ext_vector_type(8))) __bf16 bf16x8;
typedef __attribute__((ext_vector_type(8))) unsigned short u16x8;
typedef __attribute__((ext_vector_type(4))) unsigned short u16x4;

#define DEV __device__ __forceinline__

// B=4, L=2048, D=1024, H=16, HD=64, M=B*L=8192
#define CB 4
#define CL 2048
#define CD 1024
#define CM 8192

DEV float bf2f(ushort_t u) {
  unsigned int x = ((unsigned int)u) << 16;
  return __builtin_bit_cast(float, x);
}
DEV ushort_t f2bf(float f) {
  unsigned int u = __builtin_bit_cast(unsigned int, f);
  u += 0x7FFFu + ((u >> 16) & 1u);
  return (ushort_t)(u >> 16);
}
DEV void gload16(const void* g, void* l) {
  __builtin_amdgcn_global_load_lds((const __attribute__((address_space(1))) void*)g,
                                   (__attribute__((address_space(3))) void*)l, 16, 0, 0);
}
// read one 16B MFMA fragment from a [rows][64] ushort LDS tile with XOR(row&7) slot swizzle
DEV bf16x8 frag64(const ushort_t* s, int row, int slog) {
  int sl = slog ^ (row & 7);
  return __builtin_bit_cast(bf16x8, *reinterpret_cast<const u16x8*>(s + row * 64 + sl * 8));
}
// overflow-safe tanh-form GELU (|err| <= ~3e-3)
DEV float gelu_f(float x) {
  float u = 0.7978845608f * (x + 0.044715f * x * x * x);
  float e = __expf(2.0f * u);
  float th = 1.0f - 2.0f / (e + 1.0f);
  return 0.5f * x * (1.0f + th);
}

// ---------- prep: all weight transposes + rope tables in ONE dispatch ----------
DEV void tr_tile(const float* __restrict__ src, ushort_t* __restrict__ dst, int R, int C, int bx,
                 int by, int t) {
  __shared__ float tile[32][33];
  int c0 = bx * 32, r0 = by * 32;
  int tx = t & 31, ty = t >> 5;  // 32 x 8
#pragma unroll
  for (int i = 0; i < 32; i += 8) tile[ty + i][tx] = src[(size_t)(r0 + ty + i) * C + c0 + tx];
  __syncthreads();
#pragma unroll
  for (int i = 0; i < 32; i += 8) dst[(size_t)(c0 + ty + i) * R + r0 + tx] = f2bf(tile[tx][ty + i]);
}

__global__ __launch_bounds__(256) void k_prep(const float* __restrict__ W_act,
                                              const float* __restrict__ W_in,
                                              const float* __restrict__ W_qk,
                                              const float* __restrict__ W_out,
                                              const float* __restrict__ W1,
                                              const float* __restrict__ W2,
                                              ushort_t* __restrict__ WabT,
                                              ushort_t* __restrict__ WqkT,
                                              ushort_t* __restrict__ WoutT,
                                              ushort_t* __restrict__ W1T,
                                              ushort_t* __restrict__ W2T,
                                              ushort_t* __restrict__ cosT,
                                              ushort_t* __restrict__ sinT) {
  int bid = blockIdx.x, t = threadIdx.x;
  if (bid < 4096) {  // rope tables: L*512 entries
    int idx = bid * 256 + t;
    int l = idx >> 9, j = idx & 511;
    float theta = exp2f(-(float)j * (13.2877123795494f / 512.0f));
    float ang = (float)l * theta;
    float s, c;
    __sincosf(ang, &s, &c);
    cosT[idx] = f2bf(c);
    sinT[idx] = f2bf(s);
  } else if (bid < 5120) {
    int lo = bid - 4096;
    tr_tile(W_act, WabT, 1024, 1024, lo & 31, lo >> 5, t);
  } else if (bid < 6144) {
    int lo = bid - 5120;
    tr_tile(W_in, WabT + (size_t)1024 * 1024, 1024, 1024, lo & 31, lo >> 5, t);
  } else if (bid < 8192) {
    int lo = bid - 6144;
    tr_tile(W_qk, WqkT, 1024, 2048, lo & 63, lo >> 6, t);
  } else if (bid < 9216) {
    int lo = bid - 8192;
    tr_tile(W_out, WoutT, 1024, 1024, lo & 31, lo >> 5, t);
  } else if (bid < 13312) {
    int lo = bid - 9216;
    tr_tile(W1, W1T, 1024, 4096, lo & 127, lo >> 7, t);
  } else {
    int lo = bid - 13312;
    tr_tile(W2, W2T, 4096, 1024, lo & 31, lo >> 5, t);
  }
}

// ---------- layernorm: fp32 in -> bf16 out ----------
__global__ __launch_bounds__(256) void k_layernorm(const float* __restrict__ x,
                                                   const float* __restrict__ g,
                                                   const float* __restrict__ b,
                                                   ushort_t* __restrict__ out) {
  int row = blockIdx.x, t = threadIdx.x;
  const float* xr = x + (size_t)row * CD;
  f32x4 v = ((const f32x4*)xr)[t];
  float s = v.x + v.y + v.z + v.w;
  float s2 = v.x * v.x + v.y * v.y + v.z * v.z + v.w * v.w;
#pragma unroll
  for (int off = 32; off >= 1; off >>= 1) {
    s += __shfl_xor(s, off);
    s2 += __shfl_xor(s2, off);
  }
  __shared__ float red[8];
  int lane = t & 63, w = t >> 6;
  if (lane == 0) { red[w] = s; red[w + 4] = s2; }
  __syncthreads();
  s = red[0] + red[1] + red[2] + red[3];
  s2 = red[4] + red[5] + red[6] + red[7];
  float mu = s * (1.0f / CD);
  float var = s2 * (1.0f / CD) - mu * mu;
  float rs = rsqrtf(var + 1e-12f);
  f32x4 gg = ((const f32x4*)g)[t];
  f32x4 bb = ((const f32x4*)b)[t];
  u16x4 o;
  o.x = f2bf((v.x - mu) * rs * gg.x + bb.x);
  o.y = f2bf((v.y - mu) * rs * gg.y + bb.y);
  o.z = f2bf((v.z - mu) * rs * gg.z + bb.z);
  o.w = f2bf((v.w - mu) * rs * gg.w + bb.w);
  ((u16x4*)(out + (size_t)row * CD))[t] = o;
}

// ---------- bf16 GEMM (2-barrier, 128x128, 4 waves): proven 604 TF core (round 5) ----------
enum { EP_AV = 0, EP_ELU1 = 1, EP_ADDX = 3 };

template <int EP>
__global__ __launch_bounds__(256, 4) void k_gemm(const ushort_t* __restrict__ A,
                                                 const ushort_t* __restrict__ Bt, int N, int K,
                                                 const float* __restrict__ bias,
                                                 const float* __restrict__ bias2,
                                                 const float* __restrict__ addf,
                                                 float* __restrict__ outf,
                                                 ushort_t* __restrict__ outb,
                                                 ushort_t* __restrict__ out2) {
  __shared__ __align__(16) ushort_t sA[128 * 64];
  __shared__ __align__(16) ushort_t sB[128 * 64];
  const int t = threadIdx.x;
  const int lane = t & 63;
  const int w = t >> 6;
  const int wr = w >> 1, wc = w & 1;
  const int lr = lane & 15, lq = lane >> 4;
  const int m0 = blockIdx.y * 128, n0 = blockIdx.x * 128;

  f32x4 acc[4][4];
#pragma unroll
  for (int i = 0; i < 4; ++i)
#pragma unroll
    for (int j = 0; j < 4; ++j) acc[i][j] = f32x4{0.f, 0.f, 0.f, 0.f};

  for (int kt = 0; kt < K; kt += 64) {
#pragma unroll
    for (int i = 0; i < 4; ++i) {
      int c = t + i * 256;           // 1024 chunks of 16B per 128x64 tile
      int row = c >> 3;              // 8 chunks per 64-elem row
      int sl = (c & 7) ^ (row & 7);  // pre-swizzled global source, linear LDS dest
      int ldsoff = (w * 64 + i * 256) * 8;  // wave-uniform base (ushort units)
      gload16(A + (size_t)(m0 + row) * K + kt + sl * 8, sA + ldsoff);
      gload16(Bt + (size_t)(n0 + row) * K + kt + sl * 8, sB + ldsoff);
    }
    __syncthreads();
#pragma unroll
    for (int kk = 0; kk < 2; ++kk) {
      int slog = kk * 4 + lq;
      bf16x8 af[4], bfr[4];
#pragma unroll
      for (int mi = 0; mi < 4; ++mi) af[mi] = frag64(sA, wr * 64 + mi * 16 + lr, slog);
#pragma unroll
      for (int ni = 0; ni < 4; ++ni) bfr[ni] = frag64(sB, wc * 64 + ni * 16 + lr, slog);
#pragma unroll
      for (int mi = 0; mi < 4; ++mi)
#pragma unroll
        for (int ni = 0; ni < 4; ++ni)
          acc[mi][ni] =
              __builtin_amdgcn_mfma_f32_16x16x32_bf16(af[mi], bfr[ni], acc[mi][ni], 0, 0, 0);
    }
    __syncthreads();
  }

#pragma unroll
  for (int mi = 0; mi < 4; ++mi) {
#pragma unroll
    for (int ni = 0; ni < 4; ++ni) {
      int col = n0 + wc * 64 + ni * 16 + lr;
#pragma unroll
      for (int r = 0; r < 4; ++r) {
        int row = m0 + wr * 64 + mi * 16 + lq * 4 + r;
        if constexpr (EP == EP_AV) {
          if (col < 1024) {
            float vv = acc[mi][ni][r] + bias[col];
            outb[(size_t)row * 1024 + col] = f2bf(vv / (1.f + __expf(-vv)));
          } else {
            float vv = acc[mi][ni][r] + bias2[col - 1024];
            out2[(size_t)row * 1024 + (col - 1024)] = f2bf(vv);
          }
        } else if constexpr (EP == EP_ELU1) {
          float vv = acc[mi][ni][r] + bias[col];
          outb[(size_t)row * N + col] = f2bf(vv > 0.f ? vv + 1.f : __expf(vv));
        } else {  // EP_ADDX: fp32 out = addf + gemm + bias
          size_t idx = (size_t)row * N + col;
          outf[idx] = addf[idx] + acc[mi][ni][r] + bias[col];
        }
      }
    }
  }
}

// ---------- 8-phase pipelined bf16 GEMM (256x256, 8 waves, dbuf, counted vmcnt) ----------
// Template-faithful: 2 barriers/phase, lgkmcnt(0)+sched_barrier before MFMA cluster,
// per-phase half-tile staging, boundary stages t+2:A0 into just-freed buf BEFORE vmcnt(2).
// GELU epilogue (G4 only). Ledger: tile t+1's 8 loads complete at boundary; 2 stay in flight.
#define STGA8(h_, kt_, b_)                                                              \
  {                                                                                     \
    gload16(pA0 + (size_t)(h_)*131072 + (kt_), smem + (b_)*32768 + (h_)*8192 + dof0);   \
    gload16(pA1 + (size_t)(h_)*131072 + (kt_), smem + (b_)*32768 + (h_)*8192 + dof1);   \
  }
#define STGB8(h_, kt_, b_)                                                                  \
  {                                                                                         \
    gload16(pB0 + (size_t)(h_)*131072 + (kt_), smem + (b_)*32768 + 16384 + (h_)*8192 + dof0); \
    gload16(pB1 + (size_t)(h_)*131072 + (kt_), smem + (b_)*32768 + 16384 + (h_)*8192 + dof1); \
  }
#define PHASE8(mh_, nh_, RA_, BF_, RB_)                                                     \
  {                                                                                         \
    if (RA_) {                                                                              \
      _Pragma("unroll") for (int mi = 0; mi < 4; ++mi)                                      \
          _Pragma("unroll") for (int kk = 0; kk < 2; ++kk)                                  \
              af[mi][kk] = frag64(sA, wr * 128 + (mh_)*64 + mi * 16 + lr, kk * 4 + lq);     \
    }                                                                                       \
    if (RB_) {                                                                              \
      _Pragma("unroll") for (int ni = 0; ni < 2; ++ni)                                      \
          _Pragma("unroll") for (int kk = 0; kk < 2; ++kk)                                  \
              BF_[ni][kk] = frag64(sB, wc * 64 + (nh_)*32 + ni * 16 + lr, kk * 4 + lq);     \
    }                                                                                       \
    __builtin_amdgcn_s_barrier();                                                           \
    asm volatile("s_waitcnt lgkmcnt(0)" ::: "memory");                                      \
    __builtin_amdgcn_sched_barrier(0);                                                      \
    __builtin_amdgcn_s_setprio(1);                                                          \
    _Pragma("unroll") for (int kk = 0; kk < 2; ++kk)                                        \
        _Pragma("unroll") for (int mi = 0; mi < 4; ++mi)                                    \
            _Pragma("unroll") for (int ni = 0; ni < 2; ++ni)                                \
                acc[(mh_)*4 + mi][(nh_)*2 + ni] = __builtin_amdgcn_mfma_f32_16x16x32_bf16(  \
                    af[mi][kk], BF_[ni][kk], acc[(mh_)*4 + mi][(nh_)*2 + ni], 0, 0, 0);     \
    __builtin_amdgcn_s_setprio(0);                                                          \
    __builtin_amdgcn_sched_barrier(0);                                                      \
    __builtin_amdgcn_s_barrier();                                                           \
  }

__global__ __launch_bounds__(512, 1) void k_gemm8(const ushort_t* __restrict__ A,
                                                  const ushort_t* __restrict__ Bt, int N, int lda,
                                                  int ldb, int Klen, int nbx,
                                                  const float* __restrict__ bias,
                                                  ushort_t* __restrict__ outb) {
  __shared__ __align__(16) ushort_t smem[2 * 32768];  // 2 bufs x (A 32KB + B 32KB) = 128KB
  const int t = threadIdx.x;
  const int lane = t & 63, w = t >> 6;
  const int wr = w >> 2, wc = w & 3;  // 8 waves = 2M x 4N, per-wave 128x64
  const int lr = lane & 15, lq = lane >> 4;

  int bid = blockIdx.x;
  int by = bid / nbx, bx = bid - by * nbx;
  const int m0 = by << 8, n0 = bx << 8;

  // staging invariants: thread's 2 chunks per half-tile, c = t + i*512 in [0,1024)
  int c0_ = t, r0_ = c0_ >> 3, s0_ = (c0_ & 7) ^ (r0_ & 7);
  int c1_ = t + 512, r1_ = c1_ >> 3, s1_ = (c1_ & 7) ^ (r1_ & 7);
  const ushort_t* pA0 = A + (size_t)(m0 + r0_) * lda + s0_ * 8;   // lda==1024: +h*128*lda = h*131072
  const ushort_t* pA1 = A + (size_t)(m0 + r1_) * lda + s1_ * 8;
  const ushort_t* pB0 = Bt + (size_t)(n0 + r0_) * ldb + s0_ * 8;
  const ushort_t* pB1 = Bt + (size_t)(n0 + r1_) * ldb + s1_ * 8;
  const int dof0 = (w * 64) * 8;
  const int dof1 = (w * 64 + 512) * 8;

  f32x4 acc[8][4];
#pragma unroll
  for (int i = 0; i < 8; ++i)
#pragma unroll
    for (int j = 0; j < 4; ++j) acc[i][j] = f32x4{0.f, 0.f, 0.f, 0.f};

  const int NT = Klen >> 6;  // always >= 2 here
  // prologue: tile0 (all 4 halves) -> buf0; tile1:A0 -> buf1; wait tile0 (leave 2 in flight)
  STGA8(0, 0, 0);
  STGA8(1, 0, 0);
  STGB8(0, 0, 0);
  STGB8(1, 0, 0);
  STGA8(0, 64, 1);
  asm volatile("s_waitcnt vmcnt(2)" ::: "memory");
  __builtin_amdgcn_s_barrier();
  __builtin_amdgcn_sched_barrier(0);

  bf16x8 af[4][2], bf0[2][2], bf1[2][2];
  for (int tt = 0; tt < NT; ++tt) {
    const int buf = tt & 1, nbuf = buf ^ 1;
    const int ktn = (tt + 1) << 6;
    const ushort_t* sA = smem + buf * 32768;
    const ushort_t* sB = sA + 16384;
    const bool more = (tt + 1 < NT);
    // p0: quadrant (0,0); stage t+1:A1
    if (more) STGA8(1, ktn, nbuf);
    PHASE8(0, 0, 1, bf0, 1)
    // p1: quadrant (0,1); stage t+1:B0
    if (more) STGB8(0, ktn, nbuf);
    PHASE8(0, 1, 0, bf1, 1)
    // p2: quadrant (1,1); stage t+1:B1
    if (more) STGB8(1, ktn, nbuf);
    PHASE8(1, 1, 1, bf1, 0)
    // p3: quadrant (1,0); reuse af + bf0, no stage
    PHASE8(1, 0, 0, bf0, 0)
    // boundary: stage t+2:A0 into just-consumed buf, then counted wait for tile t+1
    if (more) {
      if (tt + 2 < NT) {
        STGA8(0, (tt + 2) << 6, buf);
        asm volatile("s_waitcnt vmcnt(2)" ::: "memory");
      } else {
        asm volatile("s_waitcnt vmcnt(0)" ::: "memory");
      }
      __builtin_amdgcn_s_barrier();
      __builtin_amdgcn_sched_barrier(0);
    }
  }

  // epilogue: bias + GELU(tanh) -> bf16
#pragma unroll
  for (int mi = 0; mi < 8; ++mi) {
#pragma unroll
    for (int ni = 0; ni < 4; ++ni) {
      int col = n0 + wc * 64 + ni * 16 + lr;
      float bc = bias[col];
#pragma unroll
      for (int r = 0; r < 4; ++r) {
        int row = m0 + wr * 128 + mi * 16 + lq * 4 + r;
        float vv = acc[mi][ni][r] + bc;
        outb[(size_t)row * N + col] = f2bf(gelu_f(vv));
      }
    }
  }
}

// ---------- attention reduce: per (b,h,lsplit): kv[e][d]=sum_l v[l,e]*k_rope[l,d]; kmean ----------
__global__ __launch_bounds__(256) void k_attn_reduce(const ushort_t* __restrict__ qk,
                                                     const ushort_t* __restrict__ vbf,
                                                     const ushort_t* __restrict__ cosT,
                                                     const ushort_t* __restrict__ sinT,
                                                     float* __restrict__ kvpart,
                                                     float* __restrict__ kmpart) {
  int bh = blockIdx.x >> 2, ls = blockIdx.x & 3;
  int b = bh >> 4, h = bh & 15;
  int t = threadIdx.x, lane = t & 63, w = t >> 6;

  __shared__ float kst[64][68];
  __shared__ __align__(16) ushort_t krT[64 * 64];  // [d][l] swizzled
  __shared__ __align__(16) ushort_t vT[64 * 64];   // [e][l] swizzled
  __shared__ float cst[64][32];
  __shared__ float snt[64][32];
  __shared__ float kmp[4][64];

  float kmacc = 0.f;
  f32x4 acc[4];
#pragma unroll
  for (int i = 0; i < 4; ++i) acc[i] = f32x4{0.f, 0.f, 0.f, 0.f};

  for (int c = ls * 8; c < ls * 8 + 8; ++c) {
    int l0 = c * 64;
    for (int idx = t; idx < 4096; idx += 256) {
      int l = idx >> 6, d = idx & 63;
      size_t grow = (size_t)(b * CL + l0 + l);
      float kvv = bf2f(qk[grow * 2048 + 1024 + h * 64 + d]);
      kst[l][d] = kvv;
      kmacc += kvv;
      ushort_t vv = vbf[grow * CD + h * 64 + d];
      int sl = (l >> 3) ^ (d & 7);
      vT[d * 64 + sl * 8 + (l & 7)] = vv;
    }
    for (int idx = t; idx < 2048; idx += 256) {
      int l = idx >> 5, j = idx & 31;
      size_t p = (size_t)(l0 + l) * 512 + h * 32 + j;
      cst[l][j] = bf2f(cosT[p]);
      snt[l][j] = bf2f(sinT[p]);
    }
    __syncthreads();
    for (int idx = t; idx < 4096; idx += 256) {
      int l = idx >> 6, d = idx & 63, j = d >> 1;
      float cc = cst[l][j], sn = snt[l][j];
      float kr = (d & 1) ? (kst[l][d - 1] * sn + kst[l][d] * cc)
                         : (kst[l][d] * cc - kst[l][d + 1] * sn);
      int sl = (l >> 3) ^ (d & 7);
      krT[d * 64 + sl * 8 + (l & 7)] = f2bf(kr);
    }
    __syncthreads();
#pragma unroll
    for (int kk = 0; kk < 2; ++kk) {
      int slog = kk * 4 + (lane >> 4);
      bf16x8 a = frag64(vT, w * 16 + (lane & 15), slog);  // rows = e
#pragma unroll
      for (int ni = 0; ni < 4; ++ni) {
        bf16x8 bb = frag64(krT, ni * 16 + (lane & 15), slog);  // cols = d
        acc[ni] = __builtin_amdgcn_mfma_f32_16x16x32_bf16(a, bb, acc[ni], 0, 0, 0);
      }
    }
    __syncthreads();
  }
  float* kp = kvpart + ((size_t)(bh * 4 + ls)) * 4096;
#pragma unroll
  for (int ni = 0; ni < 4; ++ni) {
    int d = ni * 16 + (lane & 15);
#pragma unroll
    for (int r = 0; r < 4; ++r) {
      int e = w * 16 + (lane >> 4) * 4 + r;
      kp[e * 64 + d] = acc[ni][r];
    }
  }
  kmp[t >> 6][t & 63] = kmacc;
  __syncthreads();
  if (t < 64) kmpart[(bh * 4 + ls) * 64 + t] = kmp[0][t] + kmp[1][t] + kmp[2][t] + kmp[3][t];
}

// ---------- reduce partials ----------
__global__ void k_kv_reduce(const float* __restrict__ kvpart, const float* __restrict__ kmpart,
                            ushort_t* __restrict__ kvT, float* __restrict__ kmean) {
  int gid = blockIdx.x * 256 + threadIdx.x;  // 64*4096
  int bh = gid >> 12;
  int r = gid & 4095;
  float s = 0.f;
#pragma unroll
  for (int ls = 0; ls < 4; ++ls) s += kvpart[((size_t)(bh * 4 + ls)) * 4096 + r];
  kvT[gid] = f2bf(s);
  if (gid < 64 * 64) {
    int bh2 = gid >> 6, d = gid & 63;
    float m = 0.f;
#pragma unroll
    for (int ls = 0; ls < 4; ++ls) m += kmpart[(bh2 * 4 + ls) * 64 + d];
    kmean[gid] = m;
  }
}

// ---------- attention out + depthwise conv4 + silu + gate: A4 = (attn + silu(conv(v))) * act ----------
__global__ __launch_bounds__(256) void k_attn_out(
    const ushort_t* __restrict__ qk, const ushort_t* __restrict__ kvT,
    const float* __restrict__ kmean, const ushort_t* __restrict__ cosT,
    const ushort_t* __restrict__ sinT, const ushort_t* __restrict__ vbf,
    const ushort_t* __restrict__ act, const float* __restrict__ convw,
    const float* __restrict__ convb, ushort_t* __restrict__ A4) {
  int bid = blockIdx.x;  // bh*32 + lt
  int bh = bid >> 5, lt = bid & 31;
  int b = bh >> 4, h = bh & 15;
  int l0 = lt * 64;
  int t = threadIdx.x, lane = t & 63, w = t >> 6;

  __shared__ float qst[64][68];
  __shared__ __align__(16) ushort_t qrT[64 * 64];
  __shared__ __align__(16) ushort_t kvs[64 * 64];
  __shared__ float cst[64][32];
  __shared__ float snt[64][32];
  __shared__ float kms[64];
  __shared__ float zrow[64];

  if (t < 64) kms[t] = kmean[bh * 64 + t];
  for (int idx = t; idx < 4096; idx += 256) {
    int l = idx >> 6, d = idx & 63;
    qst[l][d] = bf2f(qk[(size_t)(b * CL + l0 + l) * 2048 + h * 64 + d]);
    ushort_t kvv = kvT[(size_t)bh * 4096 + idx];
    int e = idx >> 6, dd = idx & 63;
    int sl = (dd >> 3) ^ (e & 7);
    kvs[e * 64 + sl * 8 + (dd & 7)] = kvv;
  }
  for (int idx = t; idx < 2048; idx += 256) {
    int l = idx >> 5, j = idx & 31;
    size_t p = (size_t)(l0 + l) * 512 + h * 32 + j;
    cst[l][j] = bf2f(cosT[p]);
    snt[l][j] = bf2f(sinT[p]);
  }
  __syncthreads();
  for (int idx = t; idx < 4096; idx += 256) {
    int l = idx >> 6, d = idx & 63, j = d >> 1;
    float cc = cst[l][j], sn = snt[l][j];
    float qr = (d & 1) ? (qst[l][d - 1] * sn + qst[l][d] * cc)
                       : (qst[l][d] * cc - qst[l][d + 1] * sn);
    int sl = (d >> 3) ^ (l & 7);
    qrT[l * 64 + sl * 8 + (d & 7)] = f2bf(qr);
  }
  if (t < 64) {
    float dot = 0.f;
#pragma unroll
    for (int d = 0; d < 64; ++d) dot += qst[t][d] * kms[d];
    zrow[t] = 1.0f / (dot * (1.0f / (float)CL) + 1e-6f);
  }
  __syncthreads();
  f32x4 acc[4];
#pragma unroll
  for (int i = 0; i < 4; ++i) acc[i] = f32x4{0.f, 0.f, 0.f, 0.f};
#pragma unroll
  for (int kk = 0; kk < 2; ++kk) {
    int slog = kk * 4 + (lane >> 4);
    bf16x8 a = frag64(qrT, w * 16 + (lane & 15), slog);
#pragma unroll
    for (int ni = 0; ni < 4; ++ni) {
      bf16x8 bb = frag64(kvs, ni * 16 + (lane & 15), slog);
      acc[ni] = __builtin_amdgcn_mfma_f32_16x16x32_bf16(a, bb, acc[ni], 0, 0, 0);
    }
  }
#pragma unroll
  for (int ni = 0; ni < 4; ++ni) {
    int e = ni * 16 + (lane & 15);
    int dcol = h * 64 + e;
#pragma unroll
    for (int r = 0; r < 4; ++r) {
      int l = w * 16 + (lane >> 4) * 4 + r;
      int lg = l0 + l;
      size_t row = (size_t)(b * CL + lg);
      float val = acc[ni][r] * zrow[l] * (1.0f / (float)CL);
      // depthwise causal conv k=4 + silu
      float cv = convb[dcol];
#pragma unroll
      for (int tt = 0; tt < 4; ++tt) {
        if (lg - 3 + tt >= 0) cv += bf2f(vbf[(row - 3 + tt) * CD + dcol]) * convw[dcol * 4 + tt];
      }
      cv = cv / (1.f + __expf(-cv));
      float a4 = (val + cv) * bf2f(act[row * CD + dcol]);
      A4[row * CD + dcol] = f2bf(a4);
    }
  }
}

// ---------- launch ----------
extern "C" void kernel_launch(void* const* d_in, const int* in_sizes, int n_in, void* d_out,
                              int out_size, void* d_ws, size_t ws_size, hipStream_t stream) {
  const float* x = (const float*)d_in[0];
  const float* ln1_g = (const float*)d_in[1];
  const float* ln1_b = (const float*)d_in[2];
  const float* ln2_g = (const float*)d_in[3];
  const float* ln2_b = (const float*)d_in[4];
  const float* W_act = (const float*)d_in[5];
  const float* b_act = (const float*)d_in[6];
  const float* W_in = (const float*)d_in[7];
  const float* b_in = (const float*)d_in[8];
  const float* W_qk = (const float*)d_in[9];
  const float* b_qk = (const float*)d_in[10];
  const float* conv_w = (const float*)d_in[11];
  const float* conv_b = (const float*)d_in[12];
  const float* W_out = (const float*)d_in[13];
  const float* b_out = (const float*)d_in[14];
  const float* W1 = (const float*)d_in[15];
  const float* b1 = (const float*)d_in[16];
  const float* W2 = (const float*)d_in[17];
  const float* b2 = (const float*)d_in[18];
  float* out = (float*)d_out;

  // ---- 160MB workspace plan (round-5/7 map, proven) ----
  char* w = (char*)d_ws;
  const size_t MB = 1024 * 1024;
  ushort_t* cosT = (ushort_t*)(w + 0 * MB);           // 2MB, last read attn_out
  ushort_t* sinT = (ushort_t*)(w + 2 * MB);           // 2MB, last read attn_out
  ushort_t* WabT = (ushort_t*)(w + 4 * MB);           // 4MB, last read G1
  ushort_t* WqkT = (ushort_t*)(w + 8 * MB);           // 4MB, last read G2
  ushort_t* WoutT = (ushort_t*)(w + 12 * MB);         // 2MB, last read G3
  ushort_t* kvTb = (ushort_t*)(w + 14 * MB);          // 0.5MB, last read attn_out
  float* kmean = (float*)(w + 14 * MB + 512 * 1024);  // 16KB, last read attn_out
  float* kmpart = (float*)(w + 14 * MB + 640 * 1024); // 64KB, last read kv_reduce
  ushort_t* mln = (ushort_t*)(w + 0 * MB);            // 16MB ALIAS, written LN2 (after G3)
  ushort_t* W1T = (ushort_t*)(w + 16 * MB);           // 8MB, last read G4
  ushort_t* W2T = (ushort_t*)(w + 24 * MB);           // 8MB, last read G5
  ushort_t* hln = (ushort_t*)(w + 32 * MB);           // 16MB, last read G1
  ushort_t* qkb = (ushort_t*)(w + 48 * MB);           // 32MB, last read attn_out
  ushort_t* actb = (ushort_t*)(w + 80 * MB);          // 16MB, last read attn_out
  ushort_t* Gb = (ushort_t*)(w + 32 * MB);            // 64MB ALIAS, written G4
  ushort_t* vb = (ushort_t*)(w + 96 * MB);            // 16MB, last read attn_out
  ushort_t* A4 = (ushort_t*)(w + 112 * MB);           // 16MB, written attn_out, read G3
  float* kvpart = (float*)(w + 112 * MB);             // 4MB ALIAS, dead after kv_reduce
  float* x2 = (float*)(w + 128 * MB);                 // 32MB, written G3, read LN2 + G5

  (void)in_sizes; (void)n_in; (void)out_size; (void)ws_size;

  // 1. prep: rope tables + all 6 weight transposes
  k_prep<<<17408, 256, 0, stream>>>(W_act, W_in, W_qk, W_out, W1, W2, WabT, WqkT, WoutT, W1T, W2T,
                                    cosT, sinT);
  // 2. LN1
  k_layernorm<<<CM, 256, 0, stream>>>(x, ln1_g, ln1_b, hln);
  // 3. G1: [act | v] = hln @ [WactT;WinT]^T, N=2048
  k_gemm<EP_AV><<<dim3(16, 64), 256, 0, stream>>>(hln, WabT, 2048, 1024, b_act, b_in, nullptr,
                                                  nullptr, actb, vb);
  // 4. G2: qk = elu(v @ WqkT^T + b_qk)+1, N=2048
  k_gemm<EP_ELU1><<<dim3(16, 64), 256, 0, stream>>>(vb, WqkT, 2048, 1024, b_qk, nullptr, nullptr,
                                                    nullptr, qkb, nullptr);
  // 5-7. attention
  k_attn_reduce<<<256, 256, 0, stream>>>(qkb, vb, cosT, sinT, kvpart, kmpart);
  k_kv_reduce<<<1024, 256, 0, stream>>>(kvpart, kmpart, kvTb, kmean);
  k_attn_out<<<2048, 256, 0, stream>>>(qkb, kvTb, kmean, cosT, sinT, vb, actb, conv_w, conv_b, A4);
  // 8. G3: x2 = x + A4 @ WoutT^T + b_out (fp32)
  k_gemm<EP_ADDX><<<dim3(8, 64), 256, 0, stream>>>(A4, WoutT, 1024, 1024, b_out, nullptr, x, x2,
                                                   nullptr, nullptr);
  // 9. LN2
  k_layernorm<<<CM, 256, 0, stream>>>(x2, ln2_g, ln2_b, mln);
  // 10. G4: Gb = gelu(mln @ W1T^T + b1), N=4096 — 8-phase 256^2 kernel, grid 32x16=512
  k_gemm8<<<512, 512, 0, stream>>>(mln, W1T, 4096, 1024, 1024, 1024, 16, b1, Gb);
  // 11. G5: out = x2 + Gb @ W2T^T + b2, N=1024, K=4096
  k_gemm<EP_ADDX><<<dim3(8, 64), 256, 0, stream>>>(Gb, W2T, 1024, 4096, b2, nullptr, x2, out,
                                                   nullptr, nullptr);
}

// Round 9
// 433.451 us; speedup vs baseline: 1.1846x; 1.0349x over previous
//
#include <hip/hip_runtime.h>
#include <math.h>

typedef unsigned short ushort_t;
typedef __attribute__((ext_vector_type(4))) float f32x4;
typedef __attribute__((ext_vector_type(8))) __bf16 bf16x8;
typedef __attribute__((ext_vector_type(8))) unsigned short u16x8;
typedef __attribute__((ext_vector_type(4))) unsigned short u16x4;

#define DEV __device__ __forceinline__

// B=4, L=2048, D=1024, H=16, HD=64, M=B*L=8192
#define CB 4
#define CL 2048
#define CD 1024
#define CM 8192

DEV float bf2f(ushort_t u) {
  unsigned int x = ((unsigned int)u) << 16;
  return __builtin_bit_cast(float, x);
}
DEV ushort_t f2bf(float f) {
  unsigned int u = __builtin_bit_cast(unsigned int, f);
  u += 0x7FFFu + ((u >> 16) & 1u);
  return (ushort_t)(u >> 16);
}
DEV void gload16(const void* g, void* l) {
  __builtin_amdgcn_global_load_lds((const __attribute__((address_space(1))) void*)g,
                                   (__attribute__((address_space(3))) void*)l, 16, 0, 0);
}
// read one 16B MFMA fragment from a [rows][64] ushort LDS tile with XOR(row&7) slot swizzle
DEV bf16x8 frag64(const ushort_t* s, int row, int slog) {
  int sl = slog ^ (row & 7);
  return __builtin_bit_cast(bf16x8, *reinterpret_cast<const u16x8*>(s + row * 64 + sl * 8));
}
// overflow-safe tanh-form GELU (|err| <= ~3e-3)
DEV float gelu_f(float x) {
  float u = 0.7978845608f * (x + 0.044715f * x * x * x);
  float e = __expf(2.0f * u);
  float th = 1.0f - 2.0f / (e + 1.0f);
  return 0.5f * x * (1.0f + th);
}

// ---------- prep: all weight transposes + rope tables in ONE dispatch ----------
DEV void tr_tile(const float* __restrict__ src, ushort_t* __restrict__ dst, int R, int C, int bx,
                 int by, int t) {
  __shared__ float tile[32][33];
  int c0 = bx * 32, r0 = by * 32;
  int tx = t & 31, ty = t >> 5;  // 32 x 8
#pragma unroll
  for (int i = 0; i < 32; i += 8) tile[ty + i][tx] = src[(size_t)(r0 + ty + i) * C + c0 + tx];
  __syncthreads();
#pragma unroll
  for (int i = 0; i < 32; i += 8) dst[(size_t)(c0 + ty + i) * R + r0 + tx] = f2bf(tile[tx][ty + i]);
}

__global__ __launch_bounds__(256) void k_prep(const float* __restrict__ W_act,
                                              const float* __restrict__ W_in,
                                              const float* __restrict__ W_qk,
                                              const float* __restrict__ W_out,
                                              const float* __restrict__ W1,
                                              const float* __restrict__ W2,
                                              ushort_t* __restrict__ WabT,
                                              ushort_t* __restrict__ WqkT,
                                              ushort_t* __restrict__ WoutT,
                                              ushort_t* __restrict__ W1T,
                                              ushort_t* __restrict__ W2T,
                                              ushort_t* __restrict__ cosT,
                                              ushort_t* __restrict__ sinT) {
  int bid = blockIdx.x, t = threadIdx.x;
  if (bid < 4096) {  // rope tables: L*512 entries
    int idx = bid * 256 + t;
    int l = idx >> 9, j = idx & 511;
    float theta = exp2f(-(float)j * (13.2877123795494f / 512.0f));
    float ang = (float)l * theta;
    float s, c;
    __sincosf(ang, &s, &c);
    cosT[idx] = f2bf(c);
    sinT[idx] = f2bf(s);
  } else if (bid < 5120) {
    int lo = bid - 4096;
    tr_tile(W_act, WabT, 1024, 1024, lo & 31, lo >> 5, t);
  } else if (bid < 6144) {
    int lo = bid - 5120;
    tr_tile(W_in, WabT + (size_t)1024 * 1024, 1024, 1024, lo & 31, lo >> 5, t);
  } else if (bid < 8192) {
    int lo = bid - 6144;
    tr_tile(W_qk, WqkT, 1024, 2048, lo & 63, lo >> 6, t);
  } else if (bid < 9216) {
    int lo = bid - 8192;
    tr_tile(W_out, WoutT, 1024, 1024, lo & 31, lo >> 5, t);
  } else if (bid < 13312) {
    int lo = bid - 9216;
    tr_tile(W1, W1T, 1024, 4096, lo & 127, lo >> 7, t);
  } else {
    int lo = bid - 13312;
    tr_tile(W2, W2T, 4096, 1024, lo & 31, lo >> 5, t);
  }
}

// ---------- layernorm: fp32 in -> bf16 out ----------
__global__ __launch_bounds__(256) void k_layernorm(const float* __restrict__ x,
                                                   const float* __restrict__ g,
                                                   const float* __restrict__ b,
                                                   ushort_t* __restrict__ out) {
  int row = blockIdx.x, t = threadIdx.x;
  const float* xr = x + (size_t)row * CD;
  f32x4 v = ((const f32x4*)xr)[t];
  float s = v.x + v.y + v.z + v.w;
  float s2 = v.x * v.x + v.y * v.y + v.z * v.z + v.w * v.w;
#pragma unroll
  for (int off = 32; off >= 1; off >>= 1) {
    s += __shfl_xor(s, off);
    s2 += __shfl_xor(s2, off);
  }
  __shared__ float red[8];
  int lane = t & 63, w = t >> 6;
  if (lane == 0) { red[w] = s; red[w + 4] = s2; }
  __syncthreads();
  s = red[0] + red[1] + red[2] + red[3];
  s2 = red[4] + red[5] + red[6] + red[7];
  float mu = s * (1.0f / CD);
  float var = s2 * (1.0f / CD) - mu * mu;
  float rs = rsqrtf(var + 1e-12f);
  f32x4 gg = ((const f32x4*)g)[t];
  f32x4 bb = ((const f32x4*)b)[t];
  u16x4 o;
  o.x = f2bf((v.x - mu) * rs * gg.x + bb.x);
  o.y = f2bf((v.y - mu) * rs * gg.y + bb.y);
  o.z = f2bf((v.z - mu) * rs * gg.z + bb.z);
  o.w = f2bf((v.w - mu) * rs * gg.w + bb.w);
  ((u16x4*)(out + (size_t)row * CD))[t] = o;
}

// ---------- bf16 GEMM (2-barrier, 128x128, 4 waves): proven 604 TF core ----------
enum { EP_AV = 0, EP_ELU1 = 1, EP_GELU = 2, EP_ADDX = 3 };

template <int EP>
__global__ __launch_bounds__(256, 4) void k_gemm(const ushort_t* __restrict__ A,
                                                 const ushort_t* __restrict__ Bt, int N, int K,
                                                 const float* __restrict__ bias,
                                                 const float* __restrict__ bias2,
                                                 const float* __restrict__ addf,
                                                 float* __restrict__ outf,
                                                 ushort_t* __restrict__ outb,
                                                 ushort_t* __restrict__ out2) {
  __shared__ __align__(16) ushort_t sA[128 * 64];
  __shared__ __align__(16) ushort_t sB[128 * 64];
  const int t = threadIdx.x;
  const int lane = t & 63;
  const int w = t >> 6;
  const int wr = w >> 1, wc = w & 1;
  const int lr = lane & 15, lq = lane >> 4;
  const int m0 = blockIdx.y * 128, n0 = blockIdx.x * 128;

  f32x4 acc[4][4];
#pragma unroll
  for (int i = 0; i < 4; ++i)
#pragma unroll
    for (int j = 0; j < 4; ++j) acc[i][j] = f32x4{0.f, 0.f, 0.f, 0.f};

  for (int kt = 0; kt < K; kt += 64) {
#pragma unroll
    for (int i = 0; i < 4; ++i) {
      int c = t + i * 256;           // 1024 chunks of 16B per 128x64 tile
      int row = c >> 3;              // 8 chunks per 64-elem row
      int sl = (c & 7) ^ (row & 7);  // pre-swizzled global source, linear LDS dest
      int ldsoff = (w * 64 + i * 256) * 8;  // wave-uniform base (ushort units)
      gload16(A + (size_t)(m0 + row) * K + kt + sl * 8, sA + ldsoff);
      gload16(Bt + (size_t)(n0 + row) * K + kt + sl * 8, sB + ldsoff);
    }
    __syncthreads();
#pragma unroll
    for (int kk = 0; kk < 2; ++kk) {
      int slog = kk * 4 + lq;
      bf16x8 af[4], bfr[4];
#pragma unroll
      for (int mi = 0; mi < 4; ++mi) af[mi] = frag64(sA, wr * 64 + mi * 16 + lr, slog);
#pragma unroll
      for (int ni = 0; ni < 4; ++ni) bfr[ni] = frag64(sB, wc * 64 + ni * 16 + lr, slog);
#pragma unroll
      for (int mi = 0; mi < 4; ++mi)
#pragma unroll
        for (int ni = 0; ni < 4; ++ni)
          acc[mi][ni] =
              __builtin_amdgcn_mfma_f32_16x16x32_bf16(af[mi], bfr[ni], acc[mi][ni], 0, 0, 0);
    }
    __syncthreads();
  }

#pragma unroll
  for (int mi = 0; mi < 4; ++mi) {
#pragma unroll
    for (int ni = 0; ni < 4; ++ni) {
      int col = n0 + wc * 64 + ni * 16 + lr;
#pragma unroll
      for (int r = 0; r < 4; ++r) {
        int row = m0 + wr * 64 + mi * 16 + lq * 4 + r;
        if constexpr (EP == EP_AV) {
          if (col < 1024) {
            float vv = acc[mi][ni][r] + bias[col];
            outb[(size_t)row * 1024 + col] = f2bf(vv / (1.f + __expf(-vv)));
          } else {
            float vv = acc[mi][ni][r] + bias2[col - 1024];
            out2[(size_t)row * 1024 + (col - 1024)] = f2bf(vv);
          }
        } else if constexpr (EP == EP_ELU1) {
          float vv = acc[mi][ni][r] + bias[col];
          outb[(size_t)row * N + col] = f2bf(vv > 0.f ? vv + 1.f : __expf(vv));
        } else if constexpr (EP == EP_GELU) {
          float vv = acc[mi][ni][r] + bias[col];
          outb[(size_t)row * N + col] = f2bf(gelu_f(vv));
        } else {  // EP_ADDX: fp32 out = addf + gemm + bias
          size_t idx = (size_t)row * N + col;
          outf[idx] = addf[idx] + acc[mi][ni][r] + bias[col];
        }
      }
    }
  }
}

// ---------- attention reduce: per (b,h,lsplit): kv[e][d]=sum_l v[l,e]*k_rope[l,d]; kmean ----------
__global__ __launch_bounds__(256) void k_attn_reduce(const ushort_t* __restrict__ qk,
                                                     const ushort_t* __restrict__ vbf,
                                                     const ushort_t* __restrict__ cosT,
                                                     const ushort_t* __restrict__ sinT,
                                                     float* __restrict__ kvpart,
                                                     float* __restrict__ kmpart) {
  int bh = blockIdx.x >> 2, ls = blockIdx.x & 3;
  int b = bh >> 4, h = bh & 15;
  int t = threadIdx.x, lane = t & 63, w = t >> 6;

  __shared__ float kst[64][68];
  __shared__ __align__(16) ushort_t krT[64 * 64];  // [d][l] swizzled
  __shared__ __align__(16) ushort_t vT[64 * 64];   // [e][l] swizzled
  __shared__ float cst[64][32];
  __shared__ float snt[64][32];
  __shared__ float kmp[4][64];

  float kmacc = 0.f;
  f32x4 acc[4];
#pragma unroll
  for (int i = 0; i < 4; ++i) acc[i] = f32x4{0.f, 0.f, 0.f, 0.f};

  for (int c = ls * 8; c < ls * 8 + 8; ++c) {
    int l0 = c * 64;
    for (int idx = t; idx < 4096; idx += 256) {
      int l = idx >> 6, d = idx & 63;
      size_t grow = (size_t)(b * CL + l0 + l);
      float kvv = bf2f(qk[grow * 2048 + 1024 + h * 64 + d]);
      kst[l][d] = kvv;
      kmacc += kvv;
      ushort_t vv = vbf[grow * CD + h * 64 + d];
      int sl = (l >> 3) ^ (d & 7);
      vT[d * 64 + sl * 8 + (l & 7)] = vv;
    }
    for (int idx = t; idx < 2048; idx += 256) {
      int l = idx >> 5, j = idx & 31;
      size_t p = (size_t)(l0 + l) * 512 + h * 32 + j;
      cst[l][j] = bf2f(cosT[p]);
      snt[l][j] = bf2f(sinT[p]);
    }
    __syncthreads();
    for (int idx = t; idx < 4096; idx += 256) {
      int l = idx >> 6, d = idx & 63, j = d >> 1;
      float cc = cst[l][j], sn = snt[l][j];
      float kr = (d & 1) ? (kst[l][d - 1] * sn + kst[l][d] * cc)
                         : (kst[l][d] * cc - kst[l][d + 1] * sn);
      int sl = (l >> 3) ^ (d & 7);
      krT[d * 64 + sl * 8 + (l & 7)] = f2bf(kr);
    }
    __syncthreads();
#pragma unroll
    for (int kk = 0; kk < 2; ++kk) {
      int slog = kk * 4 + (lane >> 4);
      bf16x8 a = frag64(vT, w * 16 + (lane & 15), slog);  // rows = e
#pragma unroll
      for (int ni = 0; ni < 4; ++ni) {
        bf16x8 bb = frag64(krT, ni * 16 + (lane & 15), slog);  // cols = d
        acc[ni] = __builtin_amdgcn_mfma_f32_16x16x32_bf16(a, bb, acc[ni], 0, 0, 0);
      }
    }
    __syncthreads();
  }
  float* kp = kvpart + ((size_t)(bh * 4 + ls)) * 4096;
#pragma unroll
  for (int ni = 0; ni < 4; ++ni) {
    int d = ni * 16 + (lane & 15);
#pragma unroll
    for (int r = 0; r < 4; ++r) {
      int e = w * 16 + (lane >> 4) * 4 + r;
      kp[e * 64 + d] = acc[ni][r];
    }
  }
  kmp[t >> 6][t & 63] = kmacc;
  __syncthreads();
  if (t < 64) kmpart[(bh * 4 + ls) * 64 + t] = kmp[0][t] + kmp[1][t] + kmp[2][t] + kmp[3][t];
}

// ---------- reduce partials ----------
__global__ void k_kv_reduce(const float* __restrict__ kvpart, const float* __restrict__ kmpart,
                            ushort_t* __restrict__ kvT, float* __restrict__ kmean) {
  int gid = blockIdx.x * 256 + threadIdx.x;  // 64*4096
  int bh = gid >> 12;
  int r = gid & 4095;
  float s = 0.f;
#pragma unroll
  for (int ls = 0; ls < 4; ++ls) s += kvpart[((size_t)(bh * 4 + ls)) * 4096 + r];
  kvT[gid] = f2bf(s);
  if (gid < 64 * 64) {
    int bh2 = gid >> 6, d = gid & 63;
    float m = 0.f;
#pragma unroll
    for (int ls = 0; ls < 4; ++ls) m += kmpart[(bh2 * 4 + ls) * 64 + d];
    kmean[gid] = m;
  }
}

// ---------- attention out + depthwise conv4 + silu + gate: A4 = (attn + silu(conv(v))) * act ----------
__global__ __launch_bounds__(256) void k_attn_out(
    const ushort_t* __restrict__ qk, const ushort_t* __restrict__ kvT,
    const float* __restrict__ kmean, const ushort_t* __restrict__ cosT,
    const ushort_t* __restrict__ sinT, const ushort_t* __restrict__ vbf,
    const ushort_t* __restrict__ act, const float* __restrict__ convw,
    const float* __restrict__ convb, ushort_t* __restrict__ A4) {
  int bid = blockIdx.x;  // bh*32 + lt
  int bh = bid >> 5, lt = bid & 31;
  int b = bh >> 4, h = bh & 15;
  int l0 = lt * 64;
  int t = threadIdx.x, lane = t & 63, w = t >> 6;

  __shared__ float qst[64][68];
  __shared__ __align__(16) ushort_t qrT[64 * 64];
  __shared__ __align__(16) ushort_t kvs[64 * 64];
  __shared__ float cst[64][32];
  __shared__ float snt[64][32];
  __shared__ float kms[64];
  __shared__ float zrow[64];

  if (t < 64) kms[t] = kmean[bh * 64 + t];
  for (int idx = t; idx < 4096; idx += 256) {
    int l = idx >> 6, d = idx & 63;
    qst[l][d] = bf2f(qk[(size_t)(b * CL + l0 + l) * 2048 + h * 64 + d]);
    ushort_t kvv = kvT[(size_t)bh * 4096 + idx];
    int e = idx >> 6, dd = idx & 63;
    int sl = (dd >> 3) ^ (e & 7);
    kvs[e * 64 + sl * 8 + (dd & 7)] = kvv;
  }
  for (int idx = t; idx < 2048; idx += 256) {
    int l = idx >> 5, j = idx & 31;
    size_t p = (size_t)(l0 + l) * 512 + h * 32 + j;
    cst[l][j] = bf2f(cosT[p]);
    snt[l][j] = bf2f(sinT[p]);
  }
  __syncthreads();
  for (int idx = t; idx < 4096; idx += 256) {
    int l = idx >> 6, d = idx & 63, j = d >> 1;
    float cc = cst[l][j], sn = snt[l][j];
    float qr = (d & 1) ? (qst[l][d - 1] * sn + qst[l][d] * cc)
                       : (qst[l][d] * cc - qst[l][d + 1] * sn);
    int sl = (d >> 3) ^ (l & 7);
    qrT[l * 64 + sl * 8 + (d & 7)] = f2bf(qr);
  }
  if (t < 64) {
    float dot = 0.f;
#pragma unroll
    for (int d = 0; d < 64; ++d) dot += qst[t][d] * kms[d];
    zrow[t] = 1.0f / (dot * (1.0f / (float)CL) + 1e-6f);
  }
  __syncthreads();
  f32x4 acc[4];
#pragma unroll
  for (int i = 0; i < 4; ++i) acc[i] = f32x4{0.f, 0.f, 0.f, 0.f};
#pragma unroll
  for (int kk = 0; kk < 2; ++kk) {
    int slog = kk * 4 + (lane >> 4);
    bf16x8 a = frag64(qrT, w * 16 + (lane & 15), slog);
#pragma unroll
    for (int ni = 0; ni < 4; ++ni) {
      bf16x8 bb = frag64(kvs, ni * 16 + (lane & 15), slog);
      acc[ni] = __builtin_amdgcn_mfma_f32_16x16x32_bf16(a, bb, acc[ni], 0, 0, 0);
    }
  }
#pragma unroll
  for (int ni = 0; ni < 4; ++ni) {
    int e = ni * 16 + (lane & 15);
    int dcol = h * 64 + e;
#pragma unroll
    for (int r = 0; r < 4; ++r) {
      int l = w * 16 + (lane >> 4) * 4 + r;
      int lg = l0 + l;
      size_t row = (size_t)(b * CL + lg);
      float val = acc[ni][r] * zrow[l] * (1.0f / (float)CL);
      // depthwise causal conv k=4 + silu
      float cv = convb[dcol];
#pragma unroll
      for (int tt = 0; tt < 4; ++tt) {
        if (lg - 3 + tt >= 0) cv += bf2f(vbf[(row - 3 + tt) * CD + dcol]) * convw[dcol * 4 + tt];
      }
      cv = cv / (1.f + __expf(-cv));
      float a4 = (val + cv) * bf2f(act[row * CD + dcol]);
      A4[row * CD + dcol] = f2bf(a4);
    }
  }
}

// ---------- launch ----------
extern "C" void kernel_launch(void* const* d_in, const int* in_sizes, int n_in, void* d_out,
                              int out_size, void* d_ws, size_t ws_size, hipStream_t stream) {
  const float* x = (const float*)d_in[0];
  const float* ln1_g = (const float*)d_in[1];
  const float* ln1_b = (const float*)d_in[2];
  const float* ln2_g = (const float*)d_in[3];
  const float* ln2_b = (const float*)d_in[4];
  const float* W_act = (const float*)d_in[5];
  const float* b_act = (const float*)d_in[6];
  const float* W_in = (const float*)d_in[7];
  const float* b_in = (const float*)d_in[8];
  const float* W_qk = (const float*)d_in[9];
  const float* b_qk = (const float*)d_in[10];
  const float* conv_w = (const float*)d_in[11];
  const float* conv_b = (const float*)d_in[12];
  const float* W_out = (const float*)d_in[13];
  const float* b_out = (const float*)d_in[14];
  const float* W1 = (const float*)d_in[15];
  const float* b1 = (const float*)d_in[16];
  const float* W2 = (const float*)d_in[17];
  const float* b2 = (const float*)d_in[18];
  float* out = (float*)d_out;

  // ---- 160MB workspace plan (round-5/7/8 map, proven) ----
  char* w = (char*)d_ws;
  const size_t MB = 1024 * 1024;
  ushort_t* cosT = (ushort_t*)(w + 0 * MB);           // 2MB, last read attn_out
  ushort_t* sinT = (ushort_t*)(w + 2 * MB);           // 2MB, last read attn_out
  ushort_t* WabT = (ushort_t*)(w + 4 * MB);           // 4MB, last read G1
  ushort_t* WqkT = (ushort_t*)(w + 8 * MB);           // 4MB, last read G2
  ushort_t* WoutT = (ushort_t*)(w + 12 * MB);         // 2MB, last read G3
  ushort_t* kvTb = (ushort_t*)(w + 14 * MB);          // 0.5MB, last read attn_out
  float* kmean = (float*)(w + 14 * MB + 512 * 1024);  // 16KB, last read attn_out
  float* kmpart = (float*)(w + 14 * MB + 640 * 1024); // 64KB, last read kv_reduce
  ushort_t* mln = (ushort_t*)(w + 0 * MB);            // 16MB ALIAS, written LN2 (after G3)
  ushort_t* W1T = (ushort_t*)(w + 16 * MB);           // 8MB, last read G4
  ushort_t* W2T = (ushort_t*)(w + 24 * MB);           // 8MB, last read G5
  ushort_t* hln = (ushort_t*)(w + 32 * MB);           // 16MB, last read G1
  ushort_t* qkb = (ushort_t*)(w + 48 * MB);           // 32MB, last read attn_out
  ushort_t* actb = (ushort_t*)(w + 80 * MB);          // 16MB, last read attn_out
  ushort_t* Gb = (ushort_t*)(w + 32 * MB);            // 64MB ALIAS, written G4
  ushort_t* vb = (ushort_t*)(w + 96 * MB);            // 16MB, last read attn_out
  ushort_t* A4 = (ushort_t*)(w + 112 * MB);           // 16MB, written attn_out, read G3
  float* kvpart = (float*)(w + 112 * MB);             // 4MB ALIAS, dead after kv_reduce
  float* x2 = (float*)(w + 128 * MB);                 // 32MB, written G3, read LN2 + G5

  (void)in_sizes; (void)n_in; (void)out_size; (void)ws_size;

  // 1. prep: rope tables + all 6 weight transposes
  k_prep<<<17408, 256, 0, stream>>>(W_act, W_in, W_qk, W_out, W1, W2, WabT, WqkT, WoutT, W1T, W2T,
                                    cosT, sinT);
  // 2. LN1
  k_layernorm<<<CM, 256, 0, stream>>>(x, ln1_g, ln1_b, hln);
  // 3. G1: [act | v] = hln @ [WactT;WinT]^T, N=2048
  k_gemm<EP_AV><<<dim3(16, 64), 256, 0, stream>>>(hln, WabT, 2048, 1024, b_act, b_in, nullptr,
                                                  nullptr, actb, vb);
  // 4. G2: qk = elu(v @ WqkT^T + b_qk)+1, N=2048
  k_gemm<EP_ELU1><<<dim3(16, 64), 256, 0, stream>>>(vb, WqkT, 2048, 1024, b_qk, nullptr, nullptr,
                                                    nullptr, qkb, nullptr);
  // 5-7. attention
  k_attn_reduce<<<256, 256, 0, stream>>>(qkb, vb, cosT, sinT, kvpart, kmpart);
  k_kv_reduce<<<1024, 256, 0, stream>>>(kvpart, kmpart, kvTb, kmean);
  k_attn_out<<<2048, 256, 0, stream>>>(qkb, kvTb, kmean, cosT, sinT, vb, actb, conv_w, conv_b, A4);
  // 8. G3: x2 = x + A4 @ WoutT^T + b_out (fp32)
  k_gemm<EP_ADDX><<<dim3(8, 64), 256, 0, stream>>>(A4, WoutT, 1024, 1024, b_out, nullptr, x, x2,
                                                   nullptr, nullptr);
  // 9. LN2
  k_layernorm<<<CM, 256, 0, stream>>>(x2, ln2_g, ln2_b, mln);
  // 10. G4: Gb = gelu(mln @ W1T^T + b1), N=4096 — 2-barrier kernel (8-phase retired)
  k_gemm<EP_GELU><<<dim3(32, 64), 256, 0, stream>>>(mln, W1T, 4096, 1024, b1, nullptr, nullptr,
                                                    nullptr, Gb, nullptr);
  // 11. G5: out = x2 + Gb @ W2T^T + b2, N=1024, K=4096
  k_gemm<EP_ADDX><<<dim3(8, 64), 256, 0, stream>>>(Gb, W2T, 1024, 4096, b2, nullptr, x2, out,
                                                   nullptr, nullptr);
}

// Round 11
// 403.445 us; speedup vs baseline: 1.2727x; 1.0744x over previous
//
#include <hip/hip_runtime.h>
#include <math.h>

typedef unsigned short ushort_t;
typedef __attribute__((ext_vector_type(4))) float f32x4;
typedef __attribute__((ext_vector_type(8))) __bf16 bf16x8;
typedef __attribute__((ext_vector_type(8))) unsigned short u16x8;
typedef __attribute__((ext_vector_type(4))) unsigned short u16x4;

#define DEV __device__ __forceinline__

// B=4, L=2048, D=1024, H=16, HD=64, M=B*L=8192
#define CB 4
#define CL 2048
#define CD 1024
#define CM 8192

DEV float bf2f(ushort_t u) {
  unsigned int x = ((unsigned int)u) << 16;
  return __builtin_bit_cast(float, x);
}
DEV ushort_t f2bf(float f) {
  unsigned int u = __builtin_bit_cast(unsigned int, f);
  u += 0x7FFFu + ((u >> 16) & 1u);
  return (ushort_t)(u >> 16);
}
DEV void gload16(const void* g, void* l) {
  __builtin_amdgcn_global_load_lds((const __attribute__((address_space(1))) void*)g,
                                   (__attribute__((address_space(3))) void*)l, 16, 0, 0);
}
// read one 16B MFMA fragment from a [rows][64] ushort LDS tile with XOR(row&7) slot swizzle
DEV bf16x8 frag64(const ushort_t* s, int row, int slog) {
  int sl = slog ^ (row & 7);
  return __builtin_bit_cast(bf16x8, *reinterpret_cast<const u16x8*>(s + row * 64 + sl * 8));
}
// overflow-safe tanh-form GELU (|err| <= ~3e-3)
DEV float gelu_f(float x) {
  float u = 0.7978845608f * (x + 0.044715f * x * x * x);
  float e = __expf(2.0f * u);
  float th = 1.0f - 2.0f / (e + 1.0f);
  return 0.5f * x * (1.0f + th);
}

// ---------- prep: weight transposes + rope tables + LN1, ONE dispatch ----------
DEV void tr_tile(const float* __restrict__ src, ushort_t* __restrict__ dst, int R, int C, int bx,
                 int by, int t) {
  __shared__ float tile[32][33];
  int c0 = bx * 32, r0 = by * 32;
  int tx = t & 31, ty = t >> 5;  // 32 x 8
#pragma unroll
  for (int i = 0; i < 32; i += 8) tile[ty + i][tx] = src[(size_t)(r0 + ty + i) * C + c0 + tx];
  __syncthreads();
#pragma unroll
  for (int i = 0; i < 32; i += 8) dst[(size_t)(c0 + ty + i) * R + r0 + tx] = f2bf(tile[tx][ty + i]);
}

DEV void ln_row(const float* __restrict__ x, const float* __restrict__ g,
                const float* __restrict__ b, ushort_t* __restrict__ out, int row, int t) {
  const float* xr = x + (size_t)row * CD;
  f32x4 v = ((const f32x4*)xr)[t];
  float s = v.x + v.y + v.z + v.w;
  float s2 = v.x * v.x + v.y * v.y + v.z * v.z + v.w * v.w;
#pragma unroll
  for (int off = 32; off >= 1; off >>= 1) {
    s += __shfl_xor(s, off);
    s2 += __shfl_xor(s2, off);
  }
  __shared__ float red[8];
  int lane = t & 63, w = t >> 6;
  if (lane == 0) { red[w] = s; red[w + 4] = s2; }
  __syncthreads();
  s = red[0] + red[1] + red[2] + red[3];
  s2 = red[4] + red[5] + red[6] + red[7];
  float mu = s * (1.0f / CD);
  float var = s2 * (1.0f / CD) - mu * mu;
  float rs = rsqrtf(var + 1e-12f);
  f32x4 gg = ((const f32x4*)g)[t];
  f32x4 bb = ((const f32x4*)b)[t];
  u16x4 o;
  o.x = f2bf((v.x - mu) * rs * gg.x + bb.x);
  o.y = f2bf((v.y - mu) * rs * gg.y + bb.y);
  o.z = f2bf((v.z - mu) * rs * gg.z + bb.z);
  o.w = f2bf((v.w - mu) * rs * gg.w + bb.w);
  ((u16x4*)(out + (size_t)row * CD))[t] = o;
}

__global__ __launch_bounds__(256) void k_prep(const float* __restrict__ W_act,
                                              const float* __restrict__ W_in,
                                              const float* __restrict__ W_qk,
                                              const float* __restrict__ W_out,
                                              const float* __restrict__ W1,
                                              const float* __restrict__ W2,
                                              const float* __restrict__ x,
                                              const float* __restrict__ ln1_g,
                                              const float* __restrict__ ln1_b,
                                              ushort_t* __restrict__ WabT,
                                              ushort_t* __restrict__ WqkT,
                                              ushort_t* __restrict__ WoutT,
                                              ushort_t* __restrict__ W1T,
                                              ushort_t* __restrict__ W2T,
                                              ushort_t* __restrict__ cosT,
                                              ushort_t* __restrict__ sinT,
                                              ushort_t* __restrict__ hln) {
  int bid = blockIdx.x, t = threadIdx.x;
  if (bid < 4096) {  // rope tables: L*512 entries
    int idx = bid * 256 + t;
    int l = idx >> 9, j = idx & 511;
    float theta = exp2f(-(float)j * (13.2877123795494f / 512.0f));
    float ang = (float)l * theta;
    float s, c;
    __sincosf(ang, &s, &c);
    cosT[idx] = f2bf(c);
    sinT[idx] = f2bf(s);
  } else if (bid < 5120) {
    int lo = bid - 4096;
    tr_tile(W_act, WabT, 1024, 1024, lo & 31, lo >> 5, t);
  } else if (bid < 6144) {
    int lo = bid - 5120;
    tr_tile(W_in, WabT + (size_t)1024 * 1024, 1024, 1024, lo & 31, lo >> 5, t);
  } else if (bid < 8192) {
    int lo = bid - 6144;
    tr_tile(W_qk, WqkT, 1024, 2048, lo & 63, lo >> 6, t);
  } else if (bid < 9216) {
    int lo = bid - 8192;
    tr_tile(W_out, WoutT, 1024, 1024, lo & 31, lo >> 5, t);
  } else if (bid < 13312) {
    int lo = bid - 9216;
    tr_tile(W1, W1T, 1024, 4096, lo & 127, lo >> 7, t);
  } else if (bid < 17408) {  // W2 [4096][1024]: needs 128 by x 32 bx = 4096 blocks (r10 bug: had 1024)
    int lo = bid - 13312;
    tr_tile(W2, W2T, 4096, 1024, lo & 31, lo >> 5, t);
  } else {  // LN1: rows 0..8191
    ln_row(x, ln1_g, ln1_b, hln, bid - 17408, t);
  }
}

// ---------- layernorm (LN2) ----------
__global__ __launch_bounds__(256) void k_layernorm(const float* __restrict__ x,
                                                   const float* __restrict__ g,
                                                   const float* __restrict__ b,
                                                   ushort_t* __restrict__ out) {
  ln_row(x, g, b, out, blockIdx.x, threadIdx.x);
}

// ---------- bf16 GEMM (2-barrier, 128x128, 4 waves): proven ~604-715 TF core ----------
enum { EP_AV = 0, EP_ELU1 = 1, EP_GELU = 2, EP_ADDX = 3 };

template <int EP>
__global__ __launch_bounds__(256, 4) void k_gemm(const ushort_t* __restrict__ A,
                                                 const ushort_t* __restrict__ Bt, int N, int K,
                                                 const float* __restrict__ bias,
                                                 const float* __restrict__ bias2,
                                                 const float* __restrict__ addf,
                                                 float* __restrict__ outf,
                                                 ushort_t* __restrict__ outb,
                                                 ushort_t* __restrict__ out2) {
  __shared__ __align__(16) ushort_t sA[128 * 64];
  __shared__ __align__(16) ushort_t sB[128 * 64];
  const int t = threadIdx.x;
  const int lane = t & 63;
  const int w = t >> 6;
  const int wr = w >> 1, wc = w & 1;
  const int lr = lane & 15, lq = lane >> 4;
  const int m0 = blockIdx.y * 128, n0 = blockIdx.x * 128;

  f32x4 acc[4][4];
#pragma unroll
  for (int i = 0; i < 4; ++i)
#pragma unroll
    for (int j = 0; j < 4; ++j) acc[i][j] = f32x4{0.f, 0.f, 0.f, 0.f};

  for (int kt = 0; kt < K; kt += 64) {
#pragma unroll
    for (int i = 0; i < 4; ++i) {
      int c = t + i * 256;           // 1024 chunks of 16B per 128x64 tile
      int row = c >> 3;              // 8 chunks per 64-elem row
      int sl = (c & 7) ^ (row & 7);  // pre-swizzled global source, linear LDS dest
      int ldsoff = (w * 64 + i * 256) * 8;  // wave-uniform base (ushort units)
      gload16(A + (size_t)(m0 + row) * K + kt + sl * 8, sA + ldsoff);
      gload16(Bt + (size_t)(n0 + row) * K + kt + sl * 8, sB + ldsoff);
    }
    __syncthreads();
#pragma unroll
    for (int kk = 0; kk < 2; ++kk) {
      int slog = kk * 4 + lq;
      bf16x8 af[4], bfr[4];
#pragma unroll
      for (int mi = 0; mi < 4; ++mi) af[mi] = frag64(sA, wr * 64 + mi * 16 + lr, slog);
#pragma unroll
      for (int ni = 0; ni < 4; ++ni) bfr[ni] = frag64(sB, wc * 64 + ni * 16 + lr, slog);
#pragma unroll
      for (int mi = 0; mi < 4; ++mi)
#pragma unroll
        for (int ni = 0; ni < 4; ++ni)
          acc[mi][ni] =
              __builtin_amdgcn_mfma_f32_16x16x32_bf16(af[mi], bfr[ni], acc[mi][ni], 0, 0, 0);
    }
    __syncthreads();
  }

#pragma unroll
  for (int mi = 0; mi < 4; ++mi) {
#pragma unroll
    for (int ni = 0; ni < 4; ++ni) {
      int col = n0 + wc * 64 + ni * 16 + lr;
#pragma unroll
      for (int r = 0; r < 4; ++r) {
        int row = m0 + wr * 64 + mi * 16 + lq * 4 + r;
        if constexpr (EP == EP_AV) {
          if (col < 1024) {
            float vv = acc[mi][ni][r] + bias[col];
            outb[(size_t)row * 1024 + col] = f2bf(vv / (1.f + __expf(-vv)));
          } else {
            float vv = acc[mi][ni][r] + bias2[col - 1024];
            out2[(size_t)row * 1024 + (col - 1024)] = f2bf(vv);
          }
        } else if constexpr (EP == EP_ELU1) {
          float vv = acc[mi][ni][r] + bias[col];
          outb[(size_t)row * N + col] = f2bf(vv > 0.f ? vv + 1.f : __expf(vv));
        } else if constexpr (EP == EP_GELU) {
          float vv = acc[mi][ni][r] + bias[col];
          outb[(size_t)row * N + col] = f2bf(gelu_f(vv));
        } else {  // EP_ADDX: fp32 out = addf + gemm + bias
          size_t idx = (size_t)row * N + col;
          outf[idx] = addf[idx] + acc[mi][ni][r] + bias[col];
        }
      }
    }
  }
}

// ---------- attention reduce: per (b,h,ls of 8): kv[e][d]=sum_l v[l,e]*k_rope[l,d]; kmean ----------
__global__ __launch_bounds__(256) void k_attn_reduce(const ushort_t* __restrict__ qk,
                                                     const ushort_t* __restrict__ vbf,
                                                     const ushort_t* __restrict__ cosT,
                                                     const ushort_t* __restrict__ sinT,
                                                     float* __restrict__ kvpart,
                                                     float* __restrict__ kmpart) {
  int bh = blockIdx.x >> 3, ls = blockIdx.x & 7;
  int b = bh >> 4, h = bh & 15;
  int t = threadIdx.x, lane = t & 63, w = t >> 6;

  __shared__ float kst[64][68];
  __shared__ __align__(16) ushort_t krT[64 * 64];  // [d][l] swizzled
  __shared__ __align__(16) ushort_t vT[64 * 64];   // [e][l] swizzled
  __shared__ float cst[64][32];
  __shared__ float snt[64][32];
  __shared__ float kmp[4][64];

  float kmacc = 0.f;
  f32x4 acc[4];
#pragma unroll
  for (int i = 0; i < 4; ++i) acc[i] = f32x4{0.f, 0.f, 0.f, 0.f};

  for (int c = ls * 4; c < ls * 4 + 4; ++c) {
    int l0 = c * 64;
    for (int idx = t; idx < 4096; idx += 256) {
      int l = idx >> 6, d = idx & 63;
      size_t grow = (size_t)(b * CL + l0 + l);
      float kvv = bf2f(qk[grow * 2048 + 1024 + h * 64 + d]);
      kst[l][d] = kvv;
      kmacc += kvv;
      ushort_t vv = vbf[grow * CD + h * 64 + d];
      int sl = (l >> 3) ^ (d & 7);
      vT[d * 64 + sl * 8 + (l & 7)] = vv;
    }
    for (int idx = t; idx < 2048; idx += 256) {
      int l = idx >> 5, j = idx & 31;
      size_t p = (size_t)(l0 + l) * 512 + h * 32 + j;
      cst[l][j] = bf2f(cosT[p]);
      snt[l][j] = bf2f(sinT[p]);
    }
    __syncthreads();
    for (int idx = t; idx < 4096; idx += 256) {
      int l = idx >> 6, d = idx & 63, j = d >> 1;
      float cc = cst[l][j], sn = snt[l][j];
      float kr = (d & 1) ? (kst[l][d - 1] * sn + kst[l][d] * cc)
                         : (kst[l][d] * cc - kst[l][d + 1] * sn);
      int sl = (l >> 3) ^ (d & 7);
      krT[d * 64 + sl * 8 + (l & 7)] = f2bf(kr);
    }
    __syncthreads();
#pragma unroll
    for (int kk = 0; kk < 2; ++kk) {
      int slog = kk * 4 + (lane >> 4);
      bf16x8 a = frag64(vT, w * 16 + (lane & 15), slog);  // rows = e
#pragma unroll
      for (int ni = 0; ni < 4; ++ni) {
        bf16x8 bb = frag64(krT, ni * 16 + (lane & 15), slog);  // cols = d
        acc[ni] = __builtin_amdgcn_mfma_f32_16x16x32_bf16(a, bb, acc[ni], 0, 0, 0);
      }
    }
    __syncthreads();
  }
  float* kp = kvpart + ((size_t)(bh * 8 + ls)) * 4096;
#pragma unroll
  for (int ni = 0; ni < 4; ++ni) {
    int d = ni * 16 + (lane & 15);
#pragma unroll
    for (int r = 0; r < 4; ++r) {
      int e = w * 16 + (lane >> 4) * 4 + r;
      kp[e * 64 + d] = acc[ni][r];
    }
  }
  kmp[t >> 6][t & 63] = kmacc;
  __syncthreads();
  if (t < 64) kmpart[(bh * 8 + ls) * 64 + t] = kmp[0][t] + kmp[1][t] + kmp[2][t] + kmp[3][t];
}

// ---------- reduce partials (8-way) ----------
__global__ void k_kv_reduce(const float* __restrict__ kvpart, const float* __restrict__ kmpart,
                            ushort_t* __restrict__ kvT, float* __restrict__ kmean) {
  int gid = blockIdx.x * 256 + threadIdx.x;  // 64*4096
  int bh = gid >> 12;
  int r = gid & 4095;
  float s = 0.f;
#pragma unroll
  for (int ls = 0; ls < 8; ++ls) s += kvpart[((size_t)(bh * 8 + ls)) * 4096 + r];
  kvT[gid] = f2bf(s);
  if (gid < 64 * 64) {
    int bh2 = gid >> 6, d = gid & 63;
    float m = 0.f;
#pragma unroll
    for (int ls = 0; ls < 8; ++ls) m += kmpart[(bh2 * 8 + ls) * 64 + d];
    kmean[gid] = m;
  }
}

// ---------- attention out + depthwise conv4 + silu + gate: A4 = (attn + silu(conv(v))) * act ----------
__global__ __launch_bounds__(256) void k_attn_out(
    const ushort_t* __restrict__ qk, const ushort_t* __restrict__ kvT,
    const float* __restrict__ kmean, const ushort_t* __restrict__ cosT,
    const ushort_t* __restrict__ sinT, const ushort_t* __restrict__ vbf,
    const ushort_t* __restrict__ act, const float* __restrict__ convw,
    const float* __restrict__ convb, ushort_t* __restrict__ A4) {
  int bid = blockIdx.x;  // bh*32 + lt
  int bh = bid >> 5, lt = bid & 31;
  int b = bh >> 4, h = bh & 15;
  int l0 = lt * 64;
  int t = threadIdx.x, lane = t & 63, w = t >> 6;

  __shared__ float qst[64][68];
  __shared__ __align__(16) ushort_t qrT[64 * 64];
  __shared__ __align__(16) ushort_t kvs[64 * 64];
  __shared__ float cst[64][32];
  __shared__ float snt[64][32];
  __shared__ float kms[64];
  __shared__ float zrow[64];

  if (t < 64) kms[t] = kmean[bh * 64 + t];
  for (int idx = t; idx < 4096; idx += 256) {
    int l = idx >> 6, d = idx & 63;
    qst[l][d] = bf2f(qk[(size_t)(b * CL + l0 + l) * 2048 + h * 64 + d]);
    ushort_t kvv = kvT[(size_t)bh * 4096 + idx];
    int e = idx >> 6, dd = idx & 63;
    int sl = (dd >> 3) ^ (e & 7);
    kvs[e * 64 + sl * 8 + (dd & 7)] = kvv;
  }
  for (int idx = t; idx < 2048; idx += 256) {
    int l = idx >> 5, j = idx & 31;
    size_t p = (size_t)(l0 + l) * 512 + h * 32 + j;
    cst[l][j] = bf2f(cosT[p]);
    snt[l][j] = bf2f(sinT[p]);
  }
  __syncthreads();
  for (int idx = t; idx < 4096; idx += 256) {
    int l = idx >> 6, d = idx & 63, j = d >> 1;
    float cc = cst[l][j], sn = snt[l][j];
    float qr = (d & 1) ? (qst[l][d - 1] * sn + qst[l][d] * cc)
                       : (qst[l][d] * cc - qst[l][d + 1] * sn);
    int sl = (d >> 3) ^ (l & 7);
    qrT[l * 64 + sl * 8 + (d & 7)] = f2bf(qr);
  }
  if (t < 64) {
    float dot = 0.f;
#pragma unroll
    for (int d = 0; d < 64; ++d) dot += qst[t][d] * kms[d];
    zrow[t] = 1.0f / (dot * (1.0f / (float)CL) + 1e-6f);
  }
  __syncthreads();
  f32x4 acc[4];
#pragma unroll
  for (int i = 0; i < 4; ++i) acc[i] = f32x4{0.f, 0.f, 0.f, 0.f};
#pragma unroll
  for (int kk = 0; kk < 2; ++kk) {
    int slog = kk * 4 + (lane >> 4);
    bf16x8 a = frag64(qrT, w * 16 + (lane & 15), slog);
#pragma unroll
    for (int ni = 0; ni < 4; ++ni) {
      bf16x8 bb = frag64(kvs, ni * 16 + (lane & 15), slog);
      acc[ni] = __builtin_amdgcn_mfma_f32_16x16x32_bf16(a, bb, acc[ni], 0, 0, 0);
    }
  }
#pragma unroll
  for (int ni = 0; ni < 4; ++ni) {
    int e = ni * 16 + (lane & 15);
    int dcol = h * 64 + e;
#pragma unroll
    for (int r = 0; r < 4; ++r) {
      int l = w * 16 + (lane >> 4) * 4 + r;
      int lg = l0 + l;
      size_t row = (size_t)(b * CL + lg);
      float val = acc[ni][r] * zrow[l] * (1.0f / (float)CL);
      // depthwise causal conv k=4 + silu
      float cv = convb[dcol];
#pragma unroll
      for (int tt = 0; tt < 4; ++tt) {
        if (lg - 3 + tt >= 0) cv += bf2f(vbf[(row - 3 + tt) * CD + dcol]) * convw[dcol * 4 + tt];
      }
      cv = cv / (1.f + __expf(-cv));
      float a4 = (val + cv) * bf2f(act[row * CD + dcol]);
      A4[row * CD + dcol] = f2bf(a4);
    }
  }
}

// ---------- launch ----------
extern "C" void kernel_launch(void* const* d_in, const int* in_sizes, int n_in, void* d_out,
                              int out_size, void* d_ws, size_t ws_size, hipStream_t stream) {
  const float* x = (const float*)d_in[0];
  const float* ln1_g = (const float*)d_in[1];
  const float* ln1_b = (const float*)d_in[2];
  const float* ln2_g = (const float*)d_in[3];
  const float* ln2_b = (const float*)d_in[4];
  const float* W_act = (const float*)d_in[5];
  const float* b_act = (const float*)d_in[6];
  const float* W_in = (const float*)d_in[7];
  const float* b_in = (const float*)d_in[8];
  const float* W_qk = (const float*)d_in[9];
  const float* b_qk = (const float*)d_in[10];
  const float* conv_w = (const float*)d_in[11];
  const float* conv_b = (const float*)d_in[12];
  const float* W_out = (const float*)d_in[13];
  const float* b_out = (const float*)d_in[14];
  const float* W1 = (const float*)d_in[15];
  const float* b1 = (const float*)d_in[16];
  const float* W2 = (const float*)d_in[17];
  const float* b2 = (const float*)d_in[18];
  float* out = (float*)d_out;

  // ---- 160MB workspace plan (round-5/7/8/9 map, proven) ----
  char* w = (char*)d_ws;
  const size_t MB = 1024 * 1024;
  ushort_t* cosT = (ushort_t*)(w + 0 * MB);           // 2MB, last read attn_out
  ushort_t* sinT = (ushort_t*)(w + 2 * MB);           // 2MB, last read attn_out
  ushort_t* WabT = (ushort_t*)(w + 4 * MB);           // 4MB, last read G1
  ushort_t* WqkT = (ushort_t*)(w + 8 * MB);           // 4MB, last read G2
  ushort_t* WoutT = (ushort_t*)(w + 12 * MB);         // 2MB, last read G3
  ushort_t* kvTb = (ushort_t*)(w + 14 * MB);          // 0.5MB, last read attn_out
  float* kmean = (float*)(w + 14 * MB + 512 * 1024);  // 16KB, last read attn_out
  float* kmpart = (float*)(w + 14 * MB + 640 * 1024); // 128KB, last read kv_reduce
  ushort_t* mln = (ushort_t*)(w + 0 * MB);            // 16MB ALIAS, written LN2 (after G3)
  ushort_t* W1T = (ushort_t*)(w + 16 * MB);           // 8MB, last read G4
  ushort_t* W2T = (ushort_t*)(w + 24 * MB);           // 8MB, last read G5
  ushort_t* hln = (ushort_t*)(w + 32 * MB);           // 16MB, last read G1
  ushort_t* qkb = (ushort_t*)(w + 48 * MB);           // 32MB, last read attn_out
  ushort_t* actb = (ushort_t*)(w + 80 * MB);          // 16MB, last read attn_out
  ushort_t* Gb = (ushort_t*)(w + 32 * MB);            // 64MB ALIAS, written G4
  ushort_t* vb = (ushort_t*)(w + 96 * MB);            // 16MB, last read attn_out
  ushort_t* A4 = (ushort_t*)(w + 112 * MB);           // 16MB, written attn_out, read G3
  float* kvpart = (float*)(w + 112 * MB);             // 8MB ALIAS, dead after kv_reduce
  float* x2 = (float*)(w + 128 * MB);                 // 32MB, written G3, read LN2 + G5

  (void)in_sizes; (void)n_in; (void)out_size; (void)ws_size;

  // 1. prep: rope tables + all 6 weight transposes + LN1 (independent work, one dispatch)
  k_prep<<<25600, 256, 0, stream>>>(W_act, W_in, W_qk, W_out, W1, W2, x, ln1_g, ln1_b, WabT, WqkT,
                                    WoutT, W1T, W2T, cosT, sinT, hln);
  // 2. G1: [act | v] = hln @ [WactT;WinT]^T, N=2048
  k_gemm<EP_AV><<<dim3(16, 64), 256, 0, stream>>>(hln, WabT, 2048, 1024, b_act, b_in, nullptr,
                                                  nullptr, actb, vb);
  // 3. G2: qk = elu(v @ WqkT^T + b_qk)+1, N=2048
  k_gemm<EP_ELU1><<<dim3(16, 64), 256, 0, stream>>>(vb, WqkT, 2048, 1024, b_qk, nullptr, nullptr,
                                                    nullptr, qkb, nullptr);
  // 4-6. attention (reduce 512 blocks: 8-way L-split)
  k_attn_reduce<<<512, 256, 0, stream>>>(qkb, vb, cosT, sinT, kvpart, kmpart);
  k_kv_reduce<<<1024, 256, 0, stream>>>(kvpart, kmpart, kvTb, kmean);
  k_attn_out<<<2048, 256, 0, stream>>>(qkb, kvTb, kmean, cosT, sinT, vb, actb, conv_w, conv_b, A4);
  // 7. G3: x2 = x + A4 @ WoutT^T + b_out (fp32)
  k_gemm<EP_ADDX><<<dim3(8, 64), 256, 0, stream>>>(A4, WoutT, 1024, 1024, b_out, nullptr, x, x2,
                                                   nullptr, nullptr);
  // 8. LN2
  k_layernorm<<<CM, 256, 0, stream>>>(x2, ln2_g, ln2_b, mln);
  // 9. G4: Gb = gelu(mln @ W1T^T + b1), N=4096
  k_gemm<EP_GELU><<<dim3(32, 64), 256, 0, stream>>>(mln, W1T, 4096, 1024, b1, nullptr, nullptr,
                                                    nullptr, Gb, nullptr);
  // 10. G5: out = x2 + Gb @ W2T^T + b2, N=1024, K=4096
  k_gemm<EP_ADDX><<<dim3(8, 64), 256, 0, stream>>>(Gb, W2T, 1024, 4096, b2, nullptr, x2, out,
                                                   nullptr, nullptr);
}